// Round 1
// baseline (883.631 us; speedup 1.0000x reference)
//
#include <hip/hip_runtime.h>
#include <float.h>
#include <stdint.h>

// WindowRouting: out[b][q][0..3] = indices of top-4 of (Q[b,q,:] . I[b,m,:]) over m.
// Scale factor dropped (order-preserving; only indices returned).
//
// Phase 1 (fp32 screen): fused tiled GEMM, per-lane running top-4 per query row
//   (each lane owns 4 q-rows x a disjoint 1/32 slice of image columns).
// Phase 2 (fp64 refine): 128 candidates/row recomputed in double (exact products
//   of fp32), re-ranked with (value desc, index asc) tie-break -> true ordering.

#define NBATCH 4
#define NQ 4096
#define NM 8192
#define KD 128
#define QT 64      // query rows per block
#define MT 128     // image rows per tile
#define KC 64      // k-chunk staged per barrier (keeps LDS at 64 KB)
#define NTHREADS 512

#define BETTER64(v, i, w, j) (((v) > (w)) || ((v) == (w) && (i) < (j)))

__global__ __launch_bounds__(NTHREADS) void wr_main(const float* __restrict__ qry,
                                                    const float* __restrict__ img,
                                                    int* __restrict__ out) {
  // A: [k][q] transposed query tile, resident all kernel. 128*64*4 = 32 KB
  // B: [k][m] transposed image k-chunk.                    64*128*4 = 32 KB
  __shared__ __align__(16) float A_lds[KD * QT];
  __shared__ __align__(16) float B_lds[KC * MT];

  const int t = (int)threadIdx.x;
  const int b = (int)blockIdx.x >> 6;            // 4 batches
  const int qbase = ((int)blockIdx.x & 63) * QT; // 64 q-tiles

  const float* qp = qry + ((size_t)b * NQ + qbase) * KD;
  const float* ip = img + (size_t)b * NM * KD;

  // ---- stage full Q tile, transposed ----
  {
    const int r = t >> 3;  // 0..63
    const int kc = t & 7;  // 0..7
    const float* src = qp + (size_t)r * KD;
#pragma unroll
    for (int i = 0; i < 4; ++i) {
      const int k0 = kc * 4 + i * 32;
      const float4 v = *(const float4*)(src + k0);
      A_lds[(k0 + 0) * QT + r] = v.x;
      A_lds[(k0 + 1) * QT + r] = v.y;
      A_lds[(k0 + 2) * QT + r] = v.z;
      A_lds[(k0 + 3) * QT + r] = v.w;
    }
  }

  const int qi = t >> 5;  // 0..15 : q-group (4 rows each)
  const int mi = t & 31;  // 0..31 : m-group (4 cols each, per tile)

  // per-(lane,row) running top-4 over this lane's column slice
  float tv[4][4];
  int ti[4][4];
#pragma unroll
  for (int j = 0; j < 4; ++j)
#pragma unroll
    for (int s = 0; s < 4; ++s) { tv[j][s] = -FLT_MAX; ti[j][s] = 0x7fffffff; }

  for (int tile = 0; tile < NM / MT; ++tile) {
    const int mbase = tile * MT;
    float acc[4][4];
#pragma unroll
    for (int j = 0; j < 4; ++j)
#pragma unroll
      for (int s = 0; s < 4; ++s) acc[j][s] = 0.0f;

    for (int kb = 0; kb < KD; kb += KC) {
      __syncthreads();  // previous chunk's readers done
      {
        const int r = t >> 2;  // 0..127
        const int kc = t & 3;
        const float* src = ip + (size_t)(mbase + r) * KD + kb;
#pragma unroll
        for (int i = 0; i < 4; ++i) {
          const int k0 = kc * 4 + i * 16;
          const float4 v = *(const float4*)(src + k0);
          B_lds[(k0 + 0) * MT + r] = v.x;
          B_lds[(k0 + 1) * MT + r] = v.y;
          B_lds[(k0 + 2) * MT + r] = v.z;
          B_lds[(k0 + 3) * MT + r] = v.w;
        }
      }
      __syncthreads();

#pragma unroll 8
      for (int k = 0; k < KC; ++k) {
        const float4 av = *(const float4*)&A_lds[(kb + k) * QT + qi * 4];
        const float4 bv = *(const float4*)&B_lds[k * MT + mi * 4];
        acc[0][0] = fmaf(av.x, bv.x, acc[0][0]);
        acc[0][1] = fmaf(av.x, bv.y, acc[0][1]);
        acc[0][2] = fmaf(av.x, bv.z, acc[0][2]);
        acc[0][3] = fmaf(av.x, bv.w, acc[0][3]);
        acc[1][0] = fmaf(av.y, bv.x, acc[1][0]);
        acc[1][1] = fmaf(av.y, bv.y, acc[1][1]);
        acc[1][2] = fmaf(av.y, bv.z, acc[1][2]);
        acc[1][3] = fmaf(av.y, bv.w, acc[1][3]);
        acc[2][0] = fmaf(av.z, bv.x, acc[2][0]);
        acc[2][1] = fmaf(av.z, bv.y, acc[2][1]);
        acc[2][2] = fmaf(av.z, bv.z, acc[2][2]);
        acc[2][3] = fmaf(av.z, bv.w, acc[2][3]);
        acc[3][0] = fmaf(av.w, bv.x, acc[3][0]);
        acc[3][1] = fmaf(av.w, bv.y, acc[3][1]);
        acc[3][2] = fmaf(av.w, bv.z, acc[3][2]);
        acc[3][3] = fmaf(av.w, bv.w, acc[3][3]);
      }
    }

    // branchless sorted-insert (strict > keeps earlier=smaller index on ties;
    // m increases monotonically within a lane)
#pragma unroll
    for (int j = 0; j < 4; ++j) {
#pragma unroll
      for (int s = 0; s < 4; ++s) {
        const float v = acc[j][s];
        const int m = mbase + mi * 4 + s;
        const bool b0 = v > tv[j][0];
        const bool b1 = v > tv[j][1];
        const bool b2 = v > tv[j][2];
        const bool b3 = v > tv[j][3];
        tv[j][3] = b2 ? tv[j][2] : (b3 ? v : tv[j][3]);
        ti[j][3] = b2 ? ti[j][2] : (b3 ? m : ti[j][3]);
        tv[j][2] = b1 ? tv[j][1] : (b2 ? v : tv[j][2]);
        ti[j][2] = b1 ? ti[j][1] : (b2 ? m : ti[j][2]);
        tv[j][1] = b0 ? tv[j][0] : (b1 ? v : tv[j][1]);
        ti[j][1] = b0 ? ti[j][0] : (b1 ? m : ti[j][1]);
        tv[j][0] = b0 ? v : tv[j][0];
        ti[j][0] = b0 ? m : ti[j][0];
      }
    }
  }

  // ---- dump candidates: 128 per row (32 m-groups x 4), disjoint by construction ----
  __syncthreads();  // all compute reads of B_lds done
  int* idx_lds = (int*)B_lds;  // [QT][128] = 32 KB, exactly B_lds
#pragma unroll
  for (int j = 0; j < 4; ++j)
#pragma unroll
    for (int s = 0; s < 4; ++s)
      idx_lds[(qi * 4 + j) * 128 + mi * 4 + s] = ti[j][s];
  __syncthreads();

  // ---- fp64 refine: 8 threads/row, 16 candidates each, local top-4 ----
  // A_lds is no longer read -> reuse for partial results.
  double* pv = (double*)A_lds;        // 512 threads * 4 doubles = 16 KB
  int* piL = (int*)(A_lds + 4096);    // 512 threads * 4 ints    =  8 KB
  {
    const int r = t >> 3;    // 0..63 local row
    const int slot = t & 7;  // 0..7
    const float* qrow = qp + (size_t)r * KD;  // global (L1/L2 hot)
    double bv[4];
    int bi[4];
#pragma unroll
    for (int e = 0; e < 4; ++e) { bv[e] = -DBL_MAX; bi[e] = 0x7fffffff; }

    for (int c = 0; c < 16; ++c) {
      const int m = idx_lds[r * 128 + slot * 16 + c];
      const float* irow = ip + (size_t)m * KD;
      double s0 = 0.0, s1 = 0.0, s2 = 0.0, s3 = 0.0;
#pragma unroll
      for (int k = 0; k < KD; k += 4) {
        const float4 xv = *(const float4*)(qrow + k);
        const float4 yv = *(const float4*)(irow + k);
        s0 = fma((double)xv.x, (double)yv.x, s0);
        s1 = fma((double)xv.y, (double)yv.y, s1);
        s2 = fma((double)xv.z, (double)yv.z, s2);
        s3 = fma((double)xv.w, (double)yv.w, s3);
      }
      const double v = (s0 + s1) + (s2 + s3);
      const bool b0 = BETTER64(v, m, bv[0], bi[0]);
      const bool b1 = BETTER64(v, m, bv[1], bi[1]);
      const bool b2 = BETTER64(v, m, bv[2], bi[2]);
      const bool b3 = BETTER64(v, m, bv[3], bi[3]);
      bv[3] = b2 ? bv[2] : (b3 ? v : bv[3]);
      bi[3] = b2 ? bi[2] : (b3 ? m : bi[3]);
      bv[2] = b1 ? bv[1] : (b2 ? v : bv[2]);
      bi[2] = b1 ? bi[1] : (b2 ? m : bi[2]);
      bv[1] = b0 ? bv[0] : (b1 ? v : bv[1]);
      bi[1] = b0 ? bi[0] : (b1 ? m : bi[1]);
      bv[0] = b0 ? v : bv[0];
      bi[0] = b0 ? m : bi[0];
    }
#pragma unroll
    for (int e = 0; e < 4; ++e) {
      pv[t * 4 + e] = bv[e];
      piL[t * 4 + e] = bi[e];
    }
  }
  __syncthreads();

  // ---- final merge: one thread per row merges 8x4 partials ----
  if (t < QT) {
    double fv[4];
    int fi[4];
#pragma unroll
    for (int e = 0; e < 4; ++e) { fv[e] = -DBL_MAX; fi[e] = 0x7fffffff; }
    for (int sl = 0; sl < 8; ++sl) {
#pragma unroll
      for (int e = 0; e < 4; ++e) {
        const double v = pv[(t * 8 + sl) * 4 + e];
        const int m = piL[(t * 8 + sl) * 4 + e];
        const bool b0 = BETTER64(v, m, fv[0], fi[0]);
        const bool b1 = BETTER64(v, m, fv[1], fi[1]);
        const bool b2 = BETTER64(v, m, fv[2], fi[2]);
        const bool b3 = BETTER64(v, m, fv[3], fi[3]);
        fv[3] = b2 ? fv[2] : (b3 ? v : fv[3]);
        fi[3] = b2 ? fi[2] : (b3 ? m : fi[3]);
        fv[2] = b1 ? fv[1] : (b2 ? v : fv[2]);
        fi[2] = b1 ? fi[1] : (b2 ? m : fi[2]);
        fv[1] = b0 ? fv[0] : (b1 ? v : fv[1]);
        fi[1] = b0 ? fi[0] : (b1 ? m : fi[1]);
        fv[0] = b0 ? v : fv[0];
        fi[0] = b0 ? m : fi[0];
      }
    }
    int4 o;
    o.x = fi[0];
    o.y = fi[1];
    o.z = fi[2];
    o.w = fi[3];
    *(int4*)(out + ((size_t)b * NQ + qbase + t) * 4) = o;
  }
}

extern "C" void kernel_launch(void* const* d_in, const int* in_sizes, int n_in,
                              void* d_out, int out_size, void* d_ws, size_t ws_size,
                              hipStream_t stream) {
  const float* qry = (const float*)d_in[0];  // (4, 4096, 128) fp32
  const float* img = (const float*)d_in[1];  // (4, 8192, 128) fp32
  int* out = (int*)d_out;                    // (4, 4096, 4) int32
  dim3 grid(NBATCH * (NQ / QT));             // 256 blocks
  wr_main<<<grid, NTHREADS, 0, stream>>>(qry, img, out);
}

// Round 2
// 229.244 us; speedup vs baseline: 3.8545x; 3.8545x over previous
//
#include <hip/hip_runtime.h>
#include <float.h>
#include <stdint.h>

// WindowRouting: out[b][q][0..3] = indices of top-4 of (Q[b,q,:] . I[b,m,:]) over m.
// Scale dropped (order-preserving).
//
// Fast path (needs ws >= 12 MB):
//   K0: convert Q,I fp32 -> bf16 in ws.
//   K1: per wave: 32 q-rows x 2048-m quarter, mfma_f32_32x32x16_bf16,
//       query frags pinned in VGPRs, image frags straight from global (no LDS
//       in main loop, no barriers). Per-lane running top-4 -> 32 candidates/row
//       -> bf16-top-8 -> fp64 refine vs fp32 originals -> exact top-4 indices.
// Fallback: round-1 fp32 LDS-tiled kernel (correct, slower).

#define NBATCH 4
#define NQ 4096
#define NM 8192
#define KD 128

typedef unsigned short ushort_t;
typedef __attribute__((ext_vector_type(8))) short bf16x8;
typedef __attribute__((ext_vector_type(16))) float f32x16;

#define BETTER64(v, i, w, j) (((v) > (w)) || ((v) == (w) && (i) < (j)))

// ---------------- K0: fp32 -> bf16 convert ----------------
__device__ inline ushort_t f2bf(float f) {
  unsigned u = __float_as_uint(f);
  u += 0x7fffu + ((u >> 16) & 1u);  // RNE
  return (ushort_t)(u >> 16);
}

__global__ __launch_bounds__(256) void wr_cvt(const float* __restrict__ qry,
                                              const float* __restrict__ img,
                                              ushort_t* __restrict__ qb,
                                              ushort_t* __restrict__ ib) {
  const int nQ4 = (NBATCH * NQ * KD) / 4;  // 524288
  const int nI4 = (NBATCH * NM * KD) / 4;  // 1048576
  const int stride = gridDim.x * blockDim.x;
  for (int t = blockIdx.x * blockDim.x + threadIdx.x; t < nQ4 + nI4; t += stride) {
    const bool isQ = t < nQ4;
    const float4 v = isQ ? ((const float4*)qry)[t] : ((const float4*)img)[t - nQ4];
    ushort4 o;
    o.x = f2bf(v.x); o.y = f2bf(v.y); o.z = f2bf(v.z); o.w = f2bf(v.w);
    if (isQ) ((ushort4*)qb)[t] = o;
    else     ((ushort4*)ib)[t - nQ4] = o;
  }
}

// ---------------- K1: MFMA screen + fp64 refine ----------------
__global__ __launch_bounds__(256) void wr_mfma(const float* __restrict__ qry,
                                               const float* __restrict__ img,
                                               const ushort_t* __restrict__ qb,
                                               const ushort_t* __restrict__ ib,
                                               int* __restrict__ out) {
  const int bid = (int)blockIdx.x;            // 0..511
  const int b = (bid & 7) >> 1;               // batch pinned to XCD pair (L2 locality)
  const int qt = ((bid >> 3) << 1) | (bid & 1);  // 0..127
  const int qbase = qt * 32;

  const int lane = (int)threadIdx.x & 63;
  const int w = (int)threadIdx.x >> 6;        // wave 0..3 -> m-quarter
  const int qc = lane & 31;                   // this lane's q within tile (C col)
  const int kh = lane >> 5;                   // k-half for A/B frags, row-half for C

  const ushort_t* Qb = qb + ((size_t)b * NQ + qbase) * KD;
  const ushort_t* Ib = ib + (size_t)b * NM * KD;

  // Query fragments for this wave's 32 q-rows: pinned in VGPRs all kernel.
  // B[n=qc][k = c*16 + kh*8 + j]
  bf16x8 bfrag[8];
  {
    const ushort_t* p = Qb + (size_t)qc * KD + kh * 8;
#pragma unroll
    for (int c = 0; c < 8; ++c) bfrag[c] = *(const bf16x8*)(p + c * 16);
  }

  float tv[4];
  int ti[4];
#pragma unroll
  for (int s = 0; s < 4; ++s) { tv[s] = -FLT_MAX; ti[s] = 0x7fffffff; }

  const int mquarter = w * 2048;
  for (int mt = 0; mt < 64; ++mt) {
    const int mbase = mquarter + mt * 32;
    // A[m = mbase+qc][k = c*16 + kh*8 + j], straight from global (L1-hot)
    const ushort_t* p = Ib + (size_t)(mbase + qc) * KD + kh * 8;
    bf16x8 afrag[8];
#pragma unroll
    for (int c = 0; c < 8; ++c) afrag[c] = *(const bf16x8*)(p + c * 16);

    f32x16 acc;
#pragma unroll
    for (int r = 0; r < 16; ++r) acc[r] = 0.0f;
#pragma unroll
    for (int c = 0; c < 8; ++c)
      acc = __builtin_amdgcn_mfma_f32_32x32x16_bf16(afrag[c], bfrag[c], acc, 0, 0, 0);

    // C/D: col = lane&31 (= q), row = (r&3) + 8*(r>>2) + 4*kh (= m within tile)
#pragma unroll
    for (int r = 0; r < 16; ++r) {
      const float v = acc[r];
      const int m = mbase + ((r & 3) + 8 * (r >> 2) + 4 * kh);
      const bool b0 = v > tv[0];
      const bool b1 = v > tv[1];
      const bool b2 = v > tv[2];
      const bool b3 = v > tv[3];
      tv[3] = b2 ? tv[2] : (b3 ? v : tv[3]);
      ti[3] = b2 ? ti[2] : (b3 ? m : ti[3]);
      tv[2] = b1 ? tv[1] : (b2 ? v : tv[2]);
      ti[2] = b1 ? ti[1] : (b2 ? m : ti[2]);
      tv[1] = b0 ? tv[0] : (b1 ? v : tv[1]);
      ti[1] = b0 ? ti[0] : (b1 ? m : ti[1]);
      tv[0] = b0 ? v : tv[0];
      ti[0] = b0 ? m : ti[0];
    }
  }

  // ---- gather 32 candidates per q-row ----
  __shared__ float cv[32][32];
  __shared__ int ci[32][32];
  __shared__ int top8[32][8];
  __shared__ double pd[32][8];
  __shared__ int pi[32][8];

  {
    const int slot = w * 8 + kh * 4;
#pragma unroll
    for (int s = 0; s < 4; ++s) { cv[qc][slot + s] = tv[s]; ci[qc][slot + s] = ti[s]; }
  }
  __syncthreads();

  // ---- bf16-top-8 of the 32 candidates (per q) ----
  if (threadIdx.x < 32) {
    const int q = (int)threadIdx.x;
    unsigned used = 0;
    for (int rsel = 0; rsel < 8; ++rsel) {
      float best = -FLT_MAX;
      int bestj = 0, bestIdx = 0x7fffffff;
      for (int j = 0; j < 32; ++j) {
        if (used & (1u << j)) continue;
        const float v = cv[q][j];
        const int id = ci[q][j];
        if (v > best || (v == best && id < bestIdx)) { best = v; bestj = j; bestIdx = id; }
      }
      used |= 1u << bestj;
      top8[q][rsel] = ci[q][bestj];
    }
  }
  __syncthreads();

  // ---- fp64 refine: 8 threads per q, one candidate each ----
  {
    const int q = (int)threadIdx.x >> 3;
    const int slot = (int)threadIdx.x & 7;
    const int m = top8[q][slot];
    const float* qrow = qry + ((size_t)b * NQ + qbase + q) * KD;
    const float* irow = img + ((size_t)b * NM + m) * KD;
    double s0 = 0.0, s1 = 0.0, s2 = 0.0, s3 = 0.0;
#pragma unroll
    for (int k = 0; k < KD; k += 4) {
      const float4 xv = *(const float4*)(qrow + k);
      const float4 yv = *(const float4*)(irow + k);
      s0 = fma((double)xv.x, (double)yv.x, s0);
      s1 = fma((double)xv.y, (double)yv.y, s1);
      s2 = fma((double)xv.z, (double)yv.z, s2);
      s3 = fma((double)xv.w, (double)yv.w, s3);
    }
    pd[q][slot] = (s0 + s1) + (s2 + s3);
    pi[q][slot] = m;
  }
  __syncthreads();

  // ---- final: exact top-4 of the 8 refined, (value desc, index asc) ----
  if (threadIdx.x < 32) {
    const int q = (int)threadIdx.x;
    double fv[4];
    int fi[4];
#pragma unroll
    for (int e = 0; e < 4; ++e) { fv[e] = -DBL_MAX; fi[e] = 0x7fffffff; }
    for (int sl = 0; sl < 8; ++sl) {
      const double v = pd[q][sl];
      const int m = pi[q][sl];
      const bool b0 = BETTER64(v, m, fv[0], fi[0]);
      const bool b1 = BETTER64(v, m, fv[1], fi[1]);
      const bool b2 = BETTER64(v, m, fv[2], fi[2]);
      const bool b3 = BETTER64(v, m, fv[3], fi[3]);
      fv[3] = b2 ? fv[2] : (b3 ? v : fv[3]);
      fi[3] = b2 ? fi[2] : (b3 ? m : fi[3]);
      fv[2] = b1 ? fv[1] : (b2 ? v : fv[2]);
      fi[2] = b1 ? fi[1] : (b2 ? m : fi[2]);
      fv[1] = b0 ? fv[0] : (b1 ? v : fv[1]);
      fi[1] = b0 ? fi[0] : (b1 ? m : fi[1]);
      fv[0] = b0 ? v : fv[0];
      fi[0] = b0 ? m : fi[0];
    }
    int4 o;
    o.x = fi[0]; o.y = fi[1]; o.z = fi[2]; o.w = fi[3];
    *(int4*)(out + ((size_t)b * NQ + qbase + q) * 4) = o;
  }
}

// ---------------- Fallback: round-1 fp32 kernel (used if ws too small) ----------------
#define QT 64
#define MT 128
#define KC 64
#define NTHREADS 512

__global__ __launch_bounds__(NTHREADS) void wr_main(const float* __restrict__ qry,
                                                    const float* __restrict__ img,
                                                    int* __restrict__ out) {
  __shared__ __align__(16) float A_lds[KD * QT];
  __shared__ __align__(16) float B_lds[KC * MT];

  const int t = (int)threadIdx.x;
  const int b = (int)blockIdx.x >> 6;
  const int qbase = ((int)blockIdx.x & 63) * QT;

  const float* qp = qry + ((size_t)b * NQ + qbase) * KD;
  const float* ip = img + (size_t)b * NM * KD;

  {
    const int r = t >> 3;
    const int kc = t & 7;
    const float* src = qp + (size_t)r * KD;
#pragma unroll
    for (int i = 0; i < 4; ++i) {
      const int k0 = kc * 4 + i * 32;
      const float4 v = *(const float4*)(src + k0);
      A_lds[(k0 + 0) * QT + r] = v.x;
      A_lds[(k0 + 1) * QT + r] = v.y;
      A_lds[(k0 + 2) * QT + r] = v.z;
      A_lds[(k0 + 3) * QT + r] = v.w;
    }
  }

  const int qi = t >> 5;
  const int mi = t & 31;

  float tv[4][4];
  int ti[4][4];
#pragma unroll
  for (int j = 0; j < 4; ++j)
#pragma unroll
    for (int s = 0; s < 4; ++s) { tv[j][s] = -FLT_MAX; ti[j][s] = 0x7fffffff; }

  for (int tile = 0; tile < NM / MT; ++tile) {
    const int mbase = tile * MT;
    float acc[4][4];
#pragma unroll
    for (int j = 0; j < 4; ++j)
#pragma unroll
      for (int s = 0; s < 4; ++s) acc[j][s] = 0.0f;

    for (int kb = 0; kb < KD; kb += KC) {
      __syncthreads();
      {
        const int r = t >> 2;
        const int kc = t & 3;
        const float* src = ip + (size_t)(mbase + r) * KD + kb;
#pragma unroll
        for (int i = 0; i < 4; ++i) {
          const int k0 = kc * 4 + i * 16;
          const float4 v = *(const float4*)(src + k0);
          B_lds[(k0 + 0) * MT + r] = v.x;
          B_lds[(k0 + 1) * MT + r] = v.y;
          B_lds[(k0 + 2) * MT + r] = v.z;
          B_lds[(k0 + 3) * MT + r] = v.w;
        }
      }
      __syncthreads();

#pragma unroll 8
      for (int k = 0; k < KC; ++k) {
        const float4 av = *(const float4*)&A_lds[(kb + k) * QT + qi * 4];
        const float4 bv = *(const float4*)&B_lds[k * MT + mi * 4];
        acc[0][0] = fmaf(av.x, bv.x, acc[0][0]);
        acc[0][1] = fmaf(av.x, bv.y, acc[0][1]);
        acc[0][2] = fmaf(av.x, bv.z, acc[0][2]);
        acc[0][3] = fmaf(av.x, bv.w, acc[0][3]);
        acc[1][0] = fmaf(av.y, bv.x, acc[1][0]);
        acc[1][1] = fmaf(av.y, bv.y, acc[1][1]);
        acc[1][2] = fmaf(av.y, bv.z, acc[1][2]);
        acc[1][3] = fmaf(av.y, bv.w, acc[1][3]);
        acc[2][0] = fmaf(av.z, bv.x, acc[2][0]);
        acc[2][1] = fmaf(av.z, bv.y, acc[2][1]);
        acc[2][2] = fmaf(av.z, bv.z, acc[2][2]);
        acc[2][3] = fmaf(av.z, bv.w, acc[2][3]);
        acc[3][0] = fmaf(av.w, bv.x, acc[3][0]);
        acc[3][1] = fmaf(av.w, bv.y, acc[3][1]);
        acc[3][2] = fmaf(av.w, bv.z, acc[3][2]);
        acc[3][3] = fmaf(av.w, bv.w, acc[3][3]);
      }
    }

#pragma unroll
    for (int j = 0; j < 4; ++j) {
#pragma unroll
      for (int s = 0; s < 4; ++s) {
        const float v = acc[j][s];
        const int m = mbase + mi * 4 + s;
        const bool b0 = v > tv[j][0];
        const bool b1 = v > tv[j][1];
        const bool b2 = v > tv[j][2];
        const bool b3 = v > tv[j][3];
        tv[j][3] = b2 ? tv[j][2] : (b3 ? v : tv[j][3]);
        ti[j][3] = b2 ? ti[j][2] : (b3 ? m : ti[j][3]);
        tv[j][2] = b1 ? tv[j][1] : (b2 ? v : tv[j][2]);
        ti[j][2] = b1 ? ti[j][1] : (b2 ? m : ti[j][2]);
        tv[j][1] = b0 ? tv[j][0] : (b1 ? v : tv[j][1]);
        ti[j][1] = b0 ? ti[j][0] : (b1 ? m : ti[j][1]);
        tv[j][0] = b0 ? v : tv[j][0];
        ti[j][0] = b0 ? m : ti[j][0];
      }
    }
  }

  __syncthreads();
  int* idx_lds = (int*)B_lds;
#pragma unroll
  for (int j = 0; j < 4; ++j)
#pragma unroll
    for (int s = 0; s < 4; ++s)
      idx_lds[(qi * 4 + j) * 128 + mi * 4 + s] = ti[j][s];
  __syncthreads();

  double* pv = (double*)A_lds;
  int* piL = (int*)(A_lds + 4096);
  {
    const int r = t >> 3;
    const int slot = t & 7;
    const float* qrow = qp + (size_t)r * KD;
    double bv[4];
    int bi[4];
#pragma unroll
    for (int e = 0; e < 4; ++e) { bv[e] = -DBL_MAX; bi[e] = 0x7fffffff; }

    for (int c = 0; c < 16; ++c) {
      const int m = idx_lds[r * 128 + slot * 16 + c];
      const float* irow = ip + (size_t)m * KD;
      double s0 = 0.0, s1 = 0.0, s2 = 0.0, s3 = 0.0;
#pragma unroll
      for (int k = 0; k < KD; k += 4) {
        const float4 xv = *(const float4*)(qrow + k);
        const float4 yv = *(const float4*)(irow + k);
        s0 = fma((double)xv.x, (double)yv.x, s0);
        s1 = fma((double)xv.y, (double)yv.y, s1);
        s2 = fma((double)xv.z, (double)yv.z, s2);
        s3 = fma((double)xv.w, (double)yv.w, s3);
      }
      const double v = (s0 + s1) + (s2 + s3);
      const bool b0 = BETTER64(v, m, bv[0], bi[0]);
      const bool b1 = BETTER64(v, m, bv[1], bi[1]);
      const bool b2 = BETTER64(v, m, bv[2], bi[2]);
      const bool b3 = BETTER64(v, m, bv[3], bi[3]);
      bv[3] = b2 ? bv[2] : (b3 ? v : bv[3]);
      bi[3] = b2 ? bi[2] : (b3 ? m : bi[3]);
      bv[2] = b1 ? bv[1] : (b2 ? v : bv[2]);
      bi[2] = b1 ? bi[1] : (b2 ? m : bi[2]);
      bv[1] = b0 ? bv[0] : (b1 ? v : bv[1]);
      bi[1] = b0 ? bi[0] : (b1 ? m : bi[1]);
      bv[0] = b0 ? v : bv[0];
      bi[0] = b0 ? m : bi[0];
    }
#pragma unroll
    for (int e = 0; e < 4; ++e) {
      pv[t * 4 + e] = bv[e];
      piL[t * 4 + e] = bi[e];
    }
  }
  __syncthreads();

  if (t < QT) {
    double fv[4];
    int fi[4];
#pragma unroll
    for (int e = 0; e < 4; ++e) { fv[e] = -DBL_MAX; fi[e] = 0x7fffffff; }
    for (int sl = 0; sl < 8; ++sl) {
#pragma unroll
      for (int e = 0; e < 4; ++e) {
        const double v = pv[(t * 8 + sl) * 4 + e];
        const int m = piL[(t * 8 + sl) * 4 + e];
        const bool b0 = BETTER64(v, m, fv[0], fi[0]);
        const bool b1 = BETTER64(v, m, fv[1], fi[1]);
        const bool b2 = BETTER64(v, m, fv[2], fi[2]);
        const bool b3 = BETTER64(v, m, fv[3], fi[3]);
        fv[3] = b2 ? fv[2] : (b3 ? v : fv[3]);
        fi[3] = b2 ? fi[2] : (b3 ? m : fi[3]);
        fv[2] = b1 ? fv[1] : (b2 ? v : fv[2]);
        fi[2] = b1 ? fi[1] : (b2 ? m : fi[2]);
        fv[1] = b0 ? fv[0] : (b1 ? v : fv[1]);
        fi[1] = b0 ? fi[0] : (b1 ? m : fi[1]);
        fv[0] = b0 ? v : fv[0];
        fi[0] = b0 ? m : fi[0];
      }
    }
    int4 o;
    o.x = fi[0]; o.y = fi[1]; o.z = fi[2]; o.w = fi[3];
    *(int4*)(out + ((size_t)b * NQ + qbase + t) * 4) = o;
  }
}

extern "C" void kernel_launch(void* const* d_in, const int* in_sizes, int n_in,
                              void* d_out, int out_size, void* d_ws, size_t ws_size,
                              hipStream_t stream) {
  const float* qry = (const float*)d_in[0];  // (4, 4096, 128) fp32
  const float* img = (const float*)d_in[1];  // (4, 8192, 128) fp32
  int* out = (int*)d_out;                    // (4, 4096, 4) int32

  const size_t qbBytes = (size_t)NBATCH * NQ * KD * sizeof(ushort_t);  // 4 MB
  const size_t ibBytes = (size_t)NBATCH * NM * KD * sizeof(ushort_t);  // 8 MB

  if (ws_size >= qbBytes + ibBytes) {
    ushort_t* qb = (ushort_t*)d_ws;
    ushort_t* ib = (ushort_t*)((char*)d_ws + qbBytes);
    wr_cvt<<<2048, 256, 0, stream>>>(qry, img, qb, ib);
    wr_mfma<<<512, 256, 0, stream>>>(qry, img, qb, ib, out);
  } else {
    wr_main<<<NBATCH * (NQ / QT), NTHREADS, 0, stream>>>(qry, img, out);
  }
}

// Round 3
// 210.909 us; speedup vs baseline: 4.1896x; 1.0869x over previous
//
#include <hip/hip_runtime.h>
#include <float.h>
#include <stdint.h>

// WindowRouting: out[b][q][0..3] = indices of top-4 of (Q[b,q,:] . I[b,m,:]) over m.
// Scale dropped (order-preserving).
//
// K0: convert Q,I fp32 -> bf16 in ws.
// K1: 256 blocks x 512 thr. Block = 64 q-rows x all 8192 m. Wave w: q-subtile
//     (w&1), m-quarter (w>>1) -> paired waves share afrag lines via L1.
//     mfma_f32_32x32x16_bf16, query frags pinned in VGPRs, image frags from
//     global with explicit double-buffer prefetch. Scores become self-indexed
//     packed keys (low 11 mantissa bits = 2047-m_local); running top-4 via
//     v_max + 3x v_med3 (4 instrs/score, two interleaved chains).
//     32 candidates/row -> top-8 -> fp64 refine vs fp32 originals -> exact.
// Fallback: round-1 fp32 LDS-tiled kernel if ws too small.

#define NBATCH 4
#define NQ 4096
#define NM 8192
#define KD 128

typedef unsigned short ushort_t;
typedef __attribute__((ext_vector_type(8))) short bf16x8;
typedef __attribute__((ext_vector_type(16))) float f32x16;

#define BETTER64(v, i, w, j) (((v) > (w)) || ((v) == (w) && (i) < (j)))

__device__ inline float fmed3(float a, float b, float c) {
#if __has_builtin(__builtin_amdgcn_fmed3f)
  return __builtin_amdgcn_fmed3f(a, b, c);
#else
  return fmaxf(fminf(a, b), fminf(fmaxf(a, b), c));
#endif
}

// ---------------- K0: fp32 -> bf16 convert ----------------
__device__ inline ushort_t f2bf(float f) {
  unsigned u = __float_as_uint(f);
  u += 0x7fffu + ((u >> 16) & 1u);  // RNE
  return (ushort_t)(u >> 16);
}

__global__ __launch_bounds__(256) void wr_cvt(const float* __restrict__ qry,
                                              const float* __restrict__ img,
                                              ushort_t* __restrict__ qb,
                                              ushort_t* __restrict__ ib) {
  const int nQ4 = (NBATCH * NQ * KD) / 4;  // 524288
  const int t = blockIdx.x * blockDim.x + threadIdx.x;  // exact grid
  const bool isQ = t < nQ4;
  const float4 v = isQ ? ((const float4*)qry)[t] : ((const float4*)img)[t - nQ4];
  ushort4 o;
  o.x = f2bf(v.x); o.y = f2bf(v.y); o.z = f2bf(v.z); o.w = f2bf(v.w);
  if (isQ) ((ushort4*)qb)[t] = o;
  else     ((ushort4*)ib)[t - nQ4] = o;
}

// ---------------- K1: MFMA screen + fp64 refine ----------------
__global__ __launch_bounds__(512) void wr_mfma(const float* __restrict__ qry,
                                               const float* __restrict__ img,
                                               const ushort_t* __restrict__ qb,
                                               const ushort_t* __restrict__ ib,
                                               int* __restrict__ out) {
  const int bid = (int)blockIdx.x;               // 0..255
  const int b = (bid & 7) >> 1;                  // batch pinned to XCD pair
  const int qt = ((bid >> 3) << 1) | (bid & 1);  // 0..63
  const int qbase = qt * 64;

  const int tid = (int)threadIdx.x;
  const int lane = tid & 63;
  const int w = tid >> 6;          // 0..7
  const int qsub = w & 1;          // q-subtile (32 rows)
  const int quarter = (w >> 1) * 2048;
  const int qc = lane & 31;
  const int kh = lane >> 5;

  const ushort_t* Qb = qb + ((size_t)b * NQ + qbase + qsub * 32) * KD;
  const ushort_t* Ib = ib + (size_t)b * NM * KD;

  // query fragments pinned: B[n=qc][k = c*16 + kh*8 + j]
  bf16x8 bfrag[8];
  {
    const ushort_t* p = Qb + (size_t)qc * KD + kh * 8;
#pragma unroll
    for (int c = 0; c < 8; ++c) bfrag[c] = *(const bf16x8*)(p + c * 16);
  }

  // cbits[r] = 2047 - m_local, m_local = mt*32 + row(r); row = (r&3)+8*(r>>2)+4*kh
  int cbits[16];
#pragma unroll
  for (int r = 0; r < 16; ++r) cbits[r] = 2047 - ((r & 3) + 8 * (r >> 2) + 4 * kh);

  float tva[4], tvb[4];  // two interleaved top-4 chains (packed keys)
#pragma unroll
  for (int s = 0; s < 4; ++s) { tva[s] = -FLT_MAX; tvb[s] = -FLT_MAX; }

  const ushort_t* pa = Ib + ((size_t)quarter + qc) * KD + kh * 8;
  const size_t tstride = (size_t)32 * KD;  // one 32-m tile, in shorts

  bf16x8 bufA[8], bufB[8];
#pragma unroll
  for (int c = 0; c < 8; ++c) bufA[c] = *(const bf16x8*)(pa + c * 16);
  pa += tstride;

  auto compute = [&](const bf16x8* buf) {
    f32x16 acc;
#pragma unroll
    for (int r = 0; r < 16; ++r) acc[r] = 0.0f;
#pragma unroll
    for (int c = 0; c < 8; ++c)
      acc = __builtin_amdgcn_mfma_f32_32x32x16_bf16(buf[c], bfrag[c], acc, 0, 0, 0);
#pragma unroll
    for (int r = 0; r < 16; ++r) {
      const unsigned kb32 =
          (__float_as_uint(acc[r]) & 0xFFFFF800u) | (unsigned)cbits[r];
      cbits[r] -= 32;
      const float key = __uint_as_float(kb32);
      if (r & 1) {
        tvb[3] = fmed3(key, tvb[2], tvb[3]);
        tvb[2] = fmed3(key, tvb[1], tvb[2]);
        tvb[1] = fmed3(key, tvb[0], tvb[1]);
        tvb[0] = fmaxf(tvb[0], key);
      } else {
        tva[3] = fmed3(key, tva[2], tva[3]);
        tva[2] = fmed3(key, tva[1], tva[2]);
        tva[1] = fmed3(key, tva[0], tva[1]);
        tva[0] = fmaxf(tva[0], key);
      }
    }
  };

  for (int mt = 0; mt < 64; mt += 2) {
#pragma unroll
    for (int c = 0; c < 8; ++c) bufB[c] = *(const bf16x8*)(pa + c * 16);
    pa += tstride;
    compute(bufA);
    if (mt + 2 < 64) {
#pragma unroll
      for (int c = 0; c < 8; ++c) bufA[c] = *(const bf16x8*)(pa + c * 16);
      pa += tstride;
    }
    compute(bufB);
  }

  // merge chain B into chain A -> per-lane top-4 keys
#pragma unroll
  for (int e = 0; e < 4; ++e) {
    const float key = tvb[e];
    tva[3] = fmed3(key, tva[2], tva[3]);
    tva[2] = fmed3(key, tva[1], tva[2]);
    tva[1] = fmed3(key, tva[0], tva[1]);
    tva[0] = fmaxf(tva[0], key);
  }

  // ---- gather 32 candidates per q-row ----
  __shared__ float ck[64][33];
  __shared__ int top8[64][8];
  __shared__ double pd[64][8];
  __shared__ int pi[64][8];

  {
    const int qrow = qsub * 32 + qc;
    const int slot = (w >> 1) * 8 + kh * 4;
#pragma unroll
    for (int s = 0; s < 4; ++s) ck[qrow][slot + s] = tva[s];
  }
  __syncthreads();

  // ---- top-8 of 32 packed keys (per q-row); decode m on the fly ----
  if (tid < 64) {
    const int q = tid;
    unsigned used = 0;
    for (int rsel = 0; rsel < 8; ++rsel) {
      float best = -FLT_MAX;
      int bestj = 0;
      for (int j = 0; j < 32; ++j) {
        if (used & (1u << j)) continue;
        const float v = ck[q][j];
        if (v > best) { best = v; bestj = j; }
      }
      used |= 1u << bestj;
      const unsigned bits = __float_as_uint(ck[q][bestj]);
      top8[q][rsel] = (bestj >> 3) * 2048 + 2047 - (int)(bits & 0x7FFu);
    }
  }
  __syncthreads();

  // ---- fp64 refine: 8 threads per q-row, one candidate each ----
  {
    const int q = tid >> 3;
    const int slot = tid & 7;
    const int m = top8[q][slot];
    const float* qrow = qry + ((size_t)b * NQ + qbase + q) * KD;
    const float* irow = img + ((size_t)b * NM + m) * KD;
    double s0 = 0.0, s1 = 0.0, s2 = 0.0, s3 = 0.0;
#pragma unroll
    for (int k = 0; k < KD; k += 4) {
      const float4 xv = *(const float4*)(qrow + k);
      const float4 yv = *(const float4*)(irow + k);
      s0 = fma((double)xv.x, (double)yv.x, s0);
      s1 = fma((double)xv.y, (double)yv.y, s1);
      s2 = fma((double)xv.z, (double)yv.z, s2);
      s3 = fma((double)xv.w, (double)yv.w, s3);
    }
    pd[q][slot] = (s0 + s1) + (s2 + s3);
    pi[q][slot] = m;
  }
  __syncthreads();

  // ---- final: exact top-4 of 8 refined, (value desc, index asc) ----
  if (tid < 64) {
    const int q = tid;
    double fv[4];
    int fi[4];
#pragma unroll
    for (int e = 0; e < 4; ++e) { fv[e] = -DBL_MAX; fi[e] = 0x7fffffff; }
    for (int sl = 0; sl < 8; ++sl) {
      const double v = pd[q][sl];
      const int m = pi[q][sl];
      const bool b0 = BETTER64(v, m, fv[0], fi[0]);
      const bool b1 = BETTER64(v, m, fv[1], fi[1]);
      const bool b2 = BETTER64(v, m, fv[2], fi[2]);
      const bool b3 = BETTER64(v, m, fv[3], fi[3]);
      fv[3] = b2 ? fv[2] : (b3 ? v : fv[3]);
      fi[3] = b2 ? fi[2] : (b3 ? m : fi[3]);
      fv[2] = b1 ? fv[1] : (b2 ? v : fv[2]);
      fi[2] = b1 ? fi[1] : (b2 ? m : fi[2]);
      fv[1] = b0 ? fv[0] : (b1 ? v : fv[1]);
      fi[1] = b0 ? fi[0] : (b1 ? m : fi[1]);
      fv[0] = b0 ? v : fv[0];
      fi[0] = b0 ? m : fi[0];
    }
    int4 o;
    o.x = fi[0]; o.y = fi[1]; o.z = fi[2]; o.w = fi[3];
    *(int4*)(out + ((size_t)b * NQ + qbase + q) * 4) = o;
  }
}

// ---------------- Fallback: fp32 LDS-tiled kernel (ws too small) ----------------
#define QT 64
#define MT 128
#define KC 64
#define NTHREADS 512

__global__ __launch_bounds__(NTHREADS) void wr_main(const float* __restrict__ qry,
                                                    const float* __restrict__ img,
                                                    int* __restrict__ out) {
  __shared__ __align__(16) float A_lds[KD * QT];
  __shared__ __align__(16) float B_lds[KC * MT];

  const int t = (int)threadIdx.x;
  const int b = (int)blockIdx.x >> 6;
  const int qbase = ((int)blockIdx.x & 63) * QT;

  const float* qp = qry + ((size_t)b * NQ + qbase) * KD;
  const float* ip = img + (size_t)b * NM * KD;

  {
    const int r = t >> 3;
    const int kc = t & 7;
    const float* src = qp + (size_t)r * KD;
#pragma unroll
    for (int i = 0; i < 4; ++i) {
      const int k0 = kc * 4 + i * 32;
      const float4 v = *(const float4*)(src + k0);
      A_lds[(k0 + 0) * QT + r] = v.x;
      A_lds[(k0 + 1) * QT + r] = v.y;
      A_lds[(k0 + 2) * QT + r] = v.z;
      A_lds[(k0 + 3) * QT + r] = v.w;
    }
  }

  const int qi = t >> 5;
  const int mi = t & 31;

  float tv[4][4];
  int ti[4][4];
#pragma unroll
  for (int j = 0; j < 4; ++j)
#pragma unroll
    for (int s = 0; s < 4; ++s) { tv[j][s] = -FLT_MAX; ti[j][s] = 0x7fffffff; }

  for (int tile = 0; tile < NM / MT; ++tile) {
    const int mbase = tile * MT;
    float acc[4][4];
#pragma unroll
    for (int j = 0; j < 4; ++j)
#pragma unroll
      for (int s = 0; s < 4; ++s) acc[j][s] = 0.0f;

    for (int kb = 0; kb < KD; kb += KC) {
      __syncthreads();
      {
        const int r = t >> 2;
        const int kc = t & 3;
        const float* src = ip + (size_t)(mbase + r) * KD + kb;
#pragma unroll
        for (int i = 0; i < 4; ++i) {
          const int k0 = kc * 4 + i * 16;
          const float4 v = *(const float4*)(src + k0);
          B_lds[(k0 + 0) * MT + r] = v.x;
          B_lds[(k0 + 1) * MT + r] = v.y;
          B_lds[(k0 + 2) * MT + r] = v.z;
          B_lds[(k0 + 3) * MT + r] = v.w;
        }
      }
      __syncthreads();

#pragma unroll 8
      for (int k = 0; k < KC; ++k) {
        const float4 av = *(const float4*)&A_lds[(kb + k) * QT + qi * 4];
        const float4 bv = *(const float4*)&B_lds[k * MT + mi * 4];
        acc[0][0] = fmaf(av.x, bv.x, acc[0][0]);
        acc[0][1] = fmaf(av.x, bv.y, acc[0][1]);
        acc[0][2] = fmaf(av.x, bv.z, acc[0][2]);
        acc[0][3] = fmaf(av.x, bv.w, acc[0][3]);
        acc[1][0] = fmaf(av.y, bv.x, acc[1][0]);
        acc[1][1] = fmaf(av.y, bv.y, acc[1][1]);
        acc[1][2] = fmaf(av.y, bv.z, acc[1][2]);
        acc[1][3] = fmaf(av.y, bv.w, acc[1][3]);
        acc[2][0] = fmaf(av.z, bv.x, acc[2][0]);
        acc[2][1] = fmaf(av.z, bv.y, acc[2][1]);
        acc[2][2] = fmaf(av.z, bv.z, acc[2][2]);
        acc[2][3] = fmaf(av.z, bv.w, acc[2][3]);
        acc[3][0] = fmaf(av.w, bv.x, acc[3][0]);
        acc[3][1] = fmaf(av.w, bv.y, acc[3][1]);
        acc[3][2] = fmaf(av.w, bv.z, acc[3][2]);
        acc[3][3] = fmaf(av.w, bv.w, acc[3][3]);
      }
    }

#pragma unroll
    for (int j = 0; j < 4; ++j) {
#pragma unroll
      for (int s = 0; s < 4; ++s) {
        const float v = acc[j][s];
        const int m = mbase + mi * 4 + s;
        const bool b0 = v > tv[j][0];
        const bool b1 = v > tv[j][1];
        const bool b2 = v > tv[j][2];
        const bool b3 = v > tv[j][3];
        tv[j][3] = b2 ? tv[j][2] : (b3 ? v : tv[j][3]);
        ti[j][3] = b2 ? ti[j][2] : (b3 ? m : ti[j][3]);
        tv[j][2] = b1 ? tv[j][1] : (b2 ? v : tv[j][2]);
        ti[j][2] = b1 ? ti[j][1] : (b2 ? m : ti[j][2]);
        tv[j][1] = b0 ? tv[j][0] : (b1 ? v : tv[j][1]);
        ti[j][1] = b0 ? ti[j][0] : (b1 ? m : ti[j][1]);
        tv[j][0] = b0 ? v : tv[j][0];
        ti[j][0] = b0 ? m : ti[j][0];
      }
    }
  }

  __syncthreads();
  int* idx_lds = (int*)B_lds;
#pragma unroll
  for (int j = 0; j < 4; ++j)
#pragma unroll
    for (int s = 0; s < 4; ++s)
      idx_lds[(qi * 4 + j) * 128 + mi * 4 + s] = ti[j][s];
  __syncthreads();

  double* pv = (double*)A_lds;
  int* piL = (int*)(A_lds + 4096);
  {
    const int r = t >> 3;
    const int slot = t & 7;
    const float* qrow = qp + (size_t)r * KD;
    double bv[4];
    int bi[4];
#pragma unroll
    for (int e = 0; e < 4; ++e) { bv[e] = -DBL_MAX; bi[e] = 0x7fffffff; }

    for (int c = 0; c < 16; ++c) {
      const int m = idx_lds[r * 128 + slot * 16 + c];
      const float* irow = ip + (size_t)m * KD;
      double s0 = 0.0, s1 = 0.0, s2 = 0.0, s3 = 0.0;
#pragma unroll
      for (int k = 0; k < KD; k += 4) {
        const float4 xv = *(const float4*)(qrow + k);
        const float4 yv = *(const float4*)(irow + k);
        s0 = fma((double)xv.x, (double)yv.x, s0);
        s1 = fma((double)xv.y, (double)yv.y, s1);
        s2 = fma((double)xv.z, (double)yv.z, s2);
        s3 = fma((double)xv.w, (double)yv.w, s3);
      }
      const double v = (s0 + s1) + (s2 + s3);
      const bool b0 = BETTER64(v, m, bv[0], bi[0]);
      const bool b1 = BETTER64(v, m, bv[1], bi[1]);
      const bool b2 = BETTER64(v, m, bv[2], bi[2]);
      const bool b3 = BETTER64(v, m, bv[3], bi[3]);
      bv[3] = b2 ? bv[2] : (b3 ? v : bv[3]);
      bi[3] = b2 ? bi[2] : (b3 ? m : bi[3]);
      bv[2] = b1 ? bv[1] : (b2 ? v : bv[2]);
      bi[2] = b1 ? bi[1] : (b2 ? m : bi[2]);
      bv[1] = b0 ? bv[0] : (b1 ? v : bv[1]);
      bi[1] = b0 ? bi[0] : (b1 ? m : bi[1]);
      bv[0] = b0 ? v : bv[0];
      bi[0] = b0 ? m : bi[0];
    }
#pragma unroll
    for (int e = 0; e < 4; ++e) {
      pv[t * 4 + e] = bv[e];
      piL[t * 4 + e] = bi[e];
    }
  }
  __syncthreads();

  if (t < QT) {
    double fv[4];
    int fi[4];
#pragma unroll
    for (int e = 0; e < 4; ++e) { fv[e] = -DBL_MAX; fi[e] = 0x7fffffff; }
    for (int sl = 0; sl < 8; ++sl) {
#pragma unroll
      for (int e = 0; e < 4; ++e) {
        const double v = pv[(t * 8 + sl) * 4 + e];
        const int m = piL[(t * 8 + sl) * 4 + e];
        const bool b0 = BETTER64(v, m, fv[0], fi[0]);
        const bool b1 = BETTER64(v, m, fv[1], fi[1]);
        const bool b2 = BETTER64(v, m, fv[2], fi[2]);
        const bool b3 = BETTER64(v, m, fv[3], fi[3]);
        fv[3] = b2 ? fv[2] : (b3 ? v : fv[3]);
        fi[3] = b2 ? fi[2] : (b3 ? m : fi[3]);
        fv[2] = b1 ? fv[1] : (b2 ? v : fv[2]);
        fi[2] = b1 ? fi[1] : (b2 ? m : fi[2]);
        fv[1] = b0 ? fv[0] : (b1 ? v : fv[1]);
        fi[1] = b0 ? fi[0] : (b1 ? m : fi[1]);
        fv[0] = b0 ? v : fv[0];
        fi[0] = b0 ? m : fi[0];
      }
    }
    int4 o;
    o.x = fi[0]; o.y = fi[1]; o.z = fi[2]; o.w = fi[3];
    *(int4*)(out + ((size_t)b * NQ + qbase + t) * 4) = o;
  }
}

extern "C" void kernel_launch(void* const* d_in, const int* in_sizes, int n_in,
                              void* d_out, int out_size, void* d_ws, size_t ws_size,
                              hipStream_t stream) {
  const float* qry = (const float*)d_in[0];  // (4, 4096, 128) fp32
  const float* img = (const float*)d_in[1];  // (4, 8192, 128) fp32
  int* out = (int*)d_out;                    // (4, 4096, 4) int32

  const size_t qbBytes = (size_t)NBATCH * NQ * KD * sizeof(ushort_t);  // 4 MB
  const size_t ibBytes = (size_t)NBATCH * NM * KD * sizeof(ushort_t);  // 8 MB

  if (ws_size >= qbBytes + ibBytes) {
    ushort_t* qb = (ushort_t*)d_ws;
    ushort_t* ib = (ushort_t*)((char*)d_ws + qbBytes);
    const int nTot4 = (NBATCH * NQ * KD + NBATCH * NM * KD) / 4;  // 1572864
    wr_cvt<<<nTot4 / 256, 256, 0, stream>>>(qry, img, qb, ib);
    wr_mfma<<<256, 512, 0, stream>>>(qry, img, qb, ib, out);
  } else {
    wr_main<<<NBATCH * (NQ / QT), NTHREADS, 0, stream>>>(qry, img, out);
  }
}

// Round 5
// 198.990 us; speedup vs baseline: 4.4406x; 1.0599x over previous
//
#include <hip/hip_runtime.h>
#include <float.h>
#include <stdint.h>

// WindowRouting: out[b][q][0..3] = indices of top-4 of (Q[b,q,:] . I[b,m,:]) over m.
// Scale dropped (order-preserving).
//
// K0 (wr_cvt): fp32 -> bf16; image additionally SWIZZLED into MFMA-fragment-
//   linear tiles so K1's loads are 64-lane-contiguous (1 KB/instr streaming).
// K1 (wr_mfma): 512 blocks x 512 thr. Block = 32 q-rows x all 8192 m; wave w
//   owns m-eighth [w*1024, w*1024+1024) = 32 tiles of 32 m. Query frags pinned
//   in VGPRs; image frags loaded fragment-linear with 2-deep double buffer.
//   Scores -> packed keys (low 11 mantissa bits = 2047 - m_local); running
//   top-4 via v_max + 3x v_med3, two interleaved chains; kh-halves merged via
//   SNAPSHOTTED shfl (read all 4 donor regs before any mutation — the R4 bug
//   was interleaving reads with merges while donors self-corrupt in lockstep)
//   -> 32 candidates/row -> rank-select top-8 -> fp64 refine vs fp32
//   originals -> exact top-4 (value desc, index asc).
// Fallback: fp32 LDS-tiled kernel if ws too small.

#define NBATCH 4
#define NQ 4096
#define NM 8192
#define KD 128

typedef unsigned short ushort_t;
typedef __attribute__((ext_vector_type(8))) short bf16x8;
typedef __attribute__((ext_vector_type(16))) float f32x16;

#define BETTER64(v, i, w, j) (((v) > (w)) || ((v) == (w) && (i) < (j)))

__device__ inline float fmed3(float a, float b, float c) {
#if __has_builtin(__builtin_amdgcn_fmed3f)
  return __builtin_amdgcn_fmed3f(a, b, c);
#else
  return fmaxf(fminf(a, b), fminf(fmaxf(a, b), c));
#endif
}

__device__ inline ushort_t f2bf(float f) {
  unsigned u = __float_as_uint(f);
  u += 0x7fffu + ((u >> 16) & 1u);  // RNE
  return (ushort_t)(u >> 16);
}

// ---------------- K0: convert + swizzle ----------------
// Query: linear bf16. Image: fragment-linear: chunk n (16B) <- tile=(n>>9),
//   c=(n>>6)&7, l=n&63, m = tile*32 + (l&31), k0 = c*16 + (l>>5)*8.
__global__ __launch_bounds__(256) void wr_cvt(const float* __restrict__ qry,
                                              const float* __restrict__ img,
                                              ushort_t* __restrict__ qb,
                                              int4* __restrict__ ib) {
  const int nQ4 = (NBATCH * NQ * KD) / 4;  // 524288 float4 chunks (query)
  const int t = blockIdx.x * 256 + threadIdx.x;
  if (t < nQ4) {
    const float4 v = ((const float4*)qry)[t];
    ushort4 o;
    o.x = f2bf(v.x); o.y = f2bf(v.y); o.z = f2bf(v.z); o.w = f2bf(v.w);
    ((ushort4*)qb)[t] = o;
  } else {
    const int n = t - nQ4;          // image chunk id, 524288 total (16B out each)
    const int b = n >> 17;          // 131072 chunks per batch
    const int rb = n & 131071;
    const int tile = rb >> 9;       // 256 tiles per batch
    const int r = rb & 511;
    const int c = r >> 6;
    const int l = r & 63;
    const int m = tile * 32 + (l & 31);
    const int k0 = c * 16 + (l >> 5) * 8;
    const float* src = img + ((size_t)(b * NM + m)) * KD + k0;
    const float4 v0 = ((const float4*)src)[0];
    const float4 v1 = ((const float4*)src)[1];
    ushort_t o[8];
    o[0] = f2bf(v0.x); o[1] = f2bf(v0.y); o[2] = f2bf(v0.z); o[3] = f2bf(v0.w);
    o[4] = f2bf(v1.x); o[5] = f2bf(v1.y); o[6] = f2bf(v1.z); o[7] = f2bf(v1.w);
    ib[n] = *(const int4*)o;
  }
}

// ---------------- K1: MFMA screen + fp64 refine ----------------
__global__ __launch_bounds__(512, 4) void wr_mfma(const float* __restrict__ qry,
                                                  const float* __restrict__ img,
                                                  const ushort_t* __restrict__ qb,
                                                  const int4* __restrict__ ib,
                                                  int* __restrict__ out) {
  const int bid = (int)blockIdx.x;               // 0..511
  const int b = (bid & 7) >> 1;                  // batch pinned to XCD pair
  const int qt = ((bid >> 3) << 1) | (bid & 1);  // 0..127
  const int qbase = qt * 32;

  const int tid = (int)threadIdx.x;
  const int lane = tid & 63;
  const int w = tid >> 6;   // 0..7 -> m-eighth
  const int qc = lane & 31;
  const int kh = lane >> 5;

  const ushort_t* Qb = qb + ((size_t)b * NQ + qbase) * KD;
  const int4* ibc = ib + (size_t)b * 131072;  // this batch's fragment chunks

  // query fragments pinned: B[n=qc][k = c*16 + kh*8 + j]
  bf16x8 bfrag[8];
  {
    const ushort_t* p = Qb + (size_t)qc * KD + kh * 8;
#pragma unroll
    for (int c = 0; c < 8; ++c) bfrag[c] = *(const bf16x8*)(p + c * 16);
  }

  float tva[4], tvb[4];
#pragma unroll
  for (int s = 0; s < 4; ++s) { tva[s] = -FLT_MAX; tvb[s] = -FLT_MAX; }

  bf16x8 bufA[8], bufB[8];

  auto loadTile = [&](bf16x8* buf, int T) {
    const int4* p = ibc + ((((w * 32 + T) << 9)) + lane);
#pragma unroll
    for (int c = 0; c < 8; ++c) buf[c] = *(const bf16x8*)(p + c * 64);
  };

  auto compute = [&](const bf16x8* buf, int vb) {
    f32x16 acc;
#pragma unroll
    for (int r = 0; r < 16; ++r) acc[r] = 0.0f;
#pragma unroll
    for (int c = 0; c < 8; ++c)
      acc = __builtin_amdgcn_mfma_f32_32x32x16_bf16(buf[c], bfrag[c], acc, 0, 0, 0);
#pragma unroll
    for (int r = 0; r < 16; ++r) {
      const int rc = (r & 3) + 8 * (r >> 2);  // inline const
      const unsigned kb =
          (__float_as_uint(acc[r]) & 0xFFFFF800u) | (unsigned)(vb - rc);
      const float key = __uint_as_float(kb);
      if (r & 1) {
        tvb[3] = fmed3(key, tvb[2], tvb[3]);
        tvb[2] = fmed3(key, tvb[1], tvb[2]);
        tvb[1] = fmed3(key, tvb[0], tvb[1]);
        tvb[0] = fmaxf(tvb[0], key);
      } else {
        tva[3] = fmed3(key, tva[2], tva[3]);
        tva[2] = fmed3(key, tva[1], tva[2]);
        tva[1] = fmed3(key, tva[0], tva[1]);
        tva[0] = fmaxf(tva[0], key);
      }
    }
  };

  // vb for tile T: 2047 - 4*kh - 32*T  (always in [1051, 2047] -> 11 bits)
  int vb = 2047 - 4 * kh;
  loadTile(bufA, 0);
  loadTile(bufB, 1);
  for (int T = 0; T < 32; T += 2) {
    compute(bufA, vb);
    if (T + 2 < 32) loadTile(bufA, T + 2);
    compute(bufB, vb - 32);
    if (T + 3 < 32) loadTile(bufB, T + 3);
    vb -= 64;
  }

  // merge chain B into chain A (lane-local, no cross-lane hazard)
#pragma unroll
  for (int e = 0; e < 4; ++e) {
    const float key = tvb[e];
    tva[3] = fmed3(key, tva[2], tva[3]);
    tva[2] = fmed3(key, tva[1], tva[2]);
    tva[1] = fmed3(key, tva[0], tva[1]);
    tva[0] = fmaxf(tva[0], key);
  }

  // merge upper kh-half into lower. SNAPSHOT FIRST: read all 4 donor regs
  // before any merge mutates tva (donor lanes self-corrupt otherwise).
  {
    float keys[4];
#pragma unroll
    for (int e = 0; e < 4; ++e) keys[e] = __shfl_down(tva[e], 32, 64);
#pragma unroll
    for (int e = 0; e < 4; ++e) {
      const float key = keys[e];
      tva[3] = fmed3(key, tva[2], tva[3]);
      tva[2] = fmed3(key, tva[1], tva[2]);
      tva[1] = fmed3(key, tva[0], tva[1]);
      tva[0] = fmaxf(tva[0], key);
    }
  }

  // ---- 32 candidates per q-row (8 eighths x 4) ----
  __shared__ float ck[32][33];
  __shared__ int top8[32][8];
  __shared__ double pd[32][8];
  __shared__ int pi[32][8];

  if (kh == 0) {
#pragma unroll
    for (int s = 0; s < 4; ++s) ck[qc][w * 4 + s] = tva[s];
  }
  __syncthreads();

  // ---- rank-select top-8 of 32 packed keys per row (ranks are unique) ----
  for (int p = tid; p < 1024; p += 512) {
    const int q = p >> 5;
    const int j = p & 31;
    const float k = ck[q][j];
    int rank = 0;
#pragma unroll 8
    for (int i = 0; i < 32; ++i) {
      const float o = ck[q][i];
      rank += (o > k) || (o == k && i < j);
    }
    if (rank < 8) {
      const unsigned bits = __float_as_uint(k);
      top8[q][rank] = (j >> 2) * 1024 + 2047 - (int)(bits & 0x7FFu);
    }
  }
  __syncthreads();

  // ---- fp64 refine: 8 threads per q-row ----
  if (tid < 256) {
    const int q = tid >> 3;
    const int slot = tid & 7;
    const int m = top8[q][slot];
    const float* qrow = qry + ((size_t)b * NQ + qbase + q) * KD;
    const float* irow = img + ((size_t)b * NM + m) * KD;
    double s0 = 0.0, s1 = 0.0, s2 = 0.0, s3 = 0.0;
#pragma unroll
    for (int k = 0; k < KD; k += 4) {
      const float4 xv = *(const float4*)(qrow + k);
      const float4 yv = *(const float4*)(irow + k);
      s0 = fma((double)xv.x, (double)yv.x, s0);
      s1 = fma((double)xv.y, (double)yv.y, s1);
      s2 = fma((double)xv.z, (double)yv.z, s2);
      s3 = fma((double)xv.w, (double)yv.w, s3);
    }
    pd[q][slot] = (s0 + s1) + (s2 + s3);
    pi[q][slot] = m;
  }
  __syncthreads();

  // ---- exact top-4 of 8 refined, (value desc, index asc) ----
  if (tid < 32) {
    const int q = tid;
    double fv[4];
    int fi[4];
#pragma unroll
    for (int e = 0; e < 4; ++e) { fv[e] = -DBL_MAX; fi[e] = 0x7fffffff; }
    for (int sl = 0; sl < 8; ++sl) {
      const double v = pd[q][sl];
      const int m = pi[q][sl];
      const bool b0 = BETTER64(v, m, fv[0], fi[0]);
      const bool b1 = BETTER64(v, m, fv[1], fi[1]);
      const bool b2 = BETTER64(v, m, fv[2], fi[2]);
      const bool b3 = BETTER64(v, m, fv[3], fi[3]);
      fv[3] = b2 ? fv[2] : (b3 ? v : fv[3]);
      fi[3] = b2 ? fi[2] : (b3 ? m : fi[3]);
      fv[2] = b1 ? fv[1] : (b2 ? v : fv[2]);
      fi[2] = b1 ? fi[1] : (b2 ? m : fi[2]);
      fv[1] = b0 ? fv[0] : (b1 ? v : fv[1]);
      fi[1] = b0 ? fi[0] : (b1 ? m : fi[1]);
      fv[0] = b0 ? v : fv[0];
      fi[0] = b0 ? m : fi[0];
    }
    int4 o;
    o.x = fi[0]; o.y = fi[1]; o.z = fi[2]; o.w = fi[3];
    *(int4*)(out + ((size_t)b * NQ + qbase + q) * 4) = o;
  }
}

// ---------------- Fallback: fp32 LDS-tiled kernel (ws too small) ----------------
#define QT 64
#define MT 128
#define KC 64
#define NTHREADS 512

__global__ __launch_bounds__(NTHREADS) void wr_main(const float* __restrict__ qry,
                                                    const float* __restrict__ img,
                                                    int* __restrict__ out) {
  __shared__ __align__(16) float A_lds[KD * QT];
  __shared__ __align__(16) float B_lds[KC * MT];

  const int t = (int)threadIdx.x;
  const int b = (int)blockIdx.x >> 6;
  const int qbase = ((int)blockIdx.x & 63) * QT;

  const float* qp = qry + ((size_t)b * NQ + qbase) * KD;
  const float* ip = img + (size_t)b * NM * KD;

  {
    const int r = t >> 3;
    const int kc = t & 7;
    const float* src = qp + (size_t)r * KD;
#pragma unroll
    for (int i = 0; i < 4; ++i) {
      const int k0 = kc * 4 + i * 32;
      const float4 v = *(const float4*)(src + k0);
      A_lds[(k0 + 0) * QT + r] = v.x;
      A_lds[(k0 + 1) * QT + r] = v.y;
      A_lds[(k0 + 2) * QT + r] = v.z;
      A_lds[(k0 + 3) * QT + r] = v.w;
    }
  }

  const int qi = t >> 5;
  const int mi = t & 31;

  float tv[4][4];
  int ti[4][4];
#pragma unroll
  for (int j = 0; j < 4; ++j)
#pragma unroll
    for (int s = 0; s < 4; ++s) { tv[j][s] = -FLT_MAX; ti[j][s] = 0x7fffffff; }

  for (int tile = 0; tile < NM / MT; ++tile) {
    const int mbase = tile * MT;
    float acc[4][4];
#pragma unroll
    for (int j = 0; j < 4; ++j)
#pragma unroll
      for (int s = 0; s < 4; ++s) acc[j][s] = 0.0f;

    for (int kb = 0; kb < KD; kb += KC) {
      __syncthreads();
      {
        const int r = t >> 2;
        const int kc = t & 3;
        const float* src = ip + (size_t)(mbase + r) * KD + kb;
#pragma unroll
        for (int i = 0; i < 4; ++i) {
          const int k0 = kc * 4 + i * 16;
          const float4 v = *(const float4*)(src + k0);
          B_lds[(k0 + 0) * MT + r] = v.x;
          B_lds[(k0 + 1) * MT + r] = v.y;
          B_lds[(k0 + 2) * MT + r] = v.z;
          B_lds[(k0 + 3) * MT + r] = v.w;
        }
      }
      __syncthreads();

#pragma unroll 8
      for (int k = 0; k < KC; ++k) {
        const float4 av = *(const float4*)&A_lds[(kb + k) * QT + qi * 4];
        const float4 bv = *(const float4*)&B_lds[k * MT + mi * 4];
        acc[0][0] = fmaf(av.x, bv.x, acc[0][0]);
        acc[0][1] = fmaf(av.x, bv.y, acc[0][1]);
        acc[0][2] = fmaf(av.x, bv.z, acc[0][2]);
        acc[0][3] = fmaf(av.x, bv.w, acc[0][3]);
        acc[1][0] = fmaf(av.y, bv.x, acc[1][0]);
        acc[1][1] = fmaf(av.y, bv.y, acc[1][1]);
        acc[1][2] = fmaf(av.y, bv.z, acc[1][2]);
        acc[1][3] = fmaf(av.y, bv.w, acc[1][3]);
        acc[2][0] = fmaf(av.z, bv.x, acc[2][0]);
        acc[2][1] = fmaf(av.z, bv.y, acc[2][1]);
        acc[2][2] = fmaf(av.z, bv.z, acc[2][2]);
        acc[2][3] = fmaf(av.z, bv.w, acc[2][3]);
        acc[3][0] = fmaf(av.w, bv.x, acc[3][0]);
        acc[3][1] = fmaf(av.w, bv.y, acc[3][1]);
        acc[3][2] = fmaf(av.w, bv.z, acc[3][2]);
        acc[3][3] = fmaf(av.w, bv.w, acc[3][3]);
      }
    }

#pragma unroll
    for (int j = 0; j < 4; ++j) {
#pragma unroll
      for (int s = 0; s < 4; ++s) {
        const float v = acc[j][s];
        const int m = mbase + mi * 4 + s;
        const bool b0 = v > tv[j][0];
        const bool b1 = v > tv[j][1];
        const bool b2 = v > tv[j][2];
        const bool b3 = v > tv[j][3];
        tv[j][3] = b2 ? tv[j][2] : (b3 ? v : tv[j][3]);
        ti[j][3] = b2 ? ti[j][2] : (b3 ? m : ti[j][3]);
        tv[j][2] = b1 ? tv[j][1] : (b2 ? v : tv[j][2]);
        ti[j][2] = b1 ? ti[j][1] : (b2 ? m : ti[j][2]);
        tv[j][1] = b0 ? tv[j][0] : (b1 ? v : tv[j][1]);
        ti[j][1] = b0 ? ti[j][0] : (b1 ? m : ti[j][1]);
        tv[j][0] = b0 ? v : tv[j][0];
        ti[j][0] = b0 ? m : ti[j][0];
      }
    }
  }

  __syncthreads();
  int* idx_lds = (int*)B_lds;
#pragma unroll
  for (int j = 0; j < 4; ++j)
#pragma unroll
    for (int s = 0; s < 4; ++s)
      idx_lds[(qi * 4 + j) * 128 + mi * 4 + s] = ti[j][s];
  __syncthreads();

  double* pv = (double*)A_lds;
  int* piL = (int*)(A_lds + 4096);
  {
    const int r = t >> 3;
    const int slot = t & 7;
    const float* qrow = qp + (size_t)r * KD;
    double bv[4];
    int bi[4];
#pragma unroll
    for (int e = 0; e < 4; ++e) { bv[e] = -DBL_MAX; bi[e] = 0x7fffffff; }

    for (int c = 0; c < 16; ++c) {
      const int m = idx_lds[r * 128 + slot * 16 + c];
      const float* irow = ip + (size_t)m * KD;
      double s0 = 0.0, s1 = 0.0, s2 = 0.0, s3 = 0.0;
#pragma unroll
      for (int k = 0; k < KD; k += 4) {
        const float4 xv = *(const float4*)(qrow + k);
        const float4 yv = *(const float4*)(irow + k);
        s0 = fma((double)xv.x, (double)yv.x, s0);
        s1 = fma((double)xv.y, (double)yv.y, s1);
        s2 = fma((double)xv.z, (double)yv.z, s2);
        s3 = fma((double)xv.w, (double)yv.w, s3);
      }
      const double v = (s0 + s1) + (s2 + s3);
      const bool b0 = BETTER64(v, m, bv[0], bi[0]);
      const bool b1 = BETTER64(v, m, bv[1], bi[1]);
      const bool b2 = BETTER64(v, m, bv[2], bi[2]);
      const bool b3 = BETTER64(v, m, bv[3], bi[3]);
      bv[3] = b2 ? bv[2] : (b3 ? v : bv[3]);
      bi[3] = b2 ? bi[2] : (b3 ? m : bi[3]);
      bv[2] = b1 ? bv[1] : (b2 ? v : bv[2]);
      bi[2] = b1 ? bi[1] : (b2 ? m : bi[2]);
      bv[1] = b0 ? bv[0] : (b1 ? v : bv[1]);
      bi[1] = b0 ? bi[0] : (b1 ? m : bi[1]);
      bv[0] = b0 ? v : bv[0];
      bi[0] = b0 ? m : bi[0];
    }
#pragma unroll
    for (int e = 0; e < 4; ++e) {
      pv[t * 4 + e] = bv[e];
      piL[t * 4 + e] = bi[e];
    }
  }
  __syncthreads();

  if (t < QT) {
    double fv[4];
    int fi[4];
#pragma unroll
    for (int e = 0; e < 4; ++e) { fv[e] = -DBL_MAX; fi[e] = 0x7fffffff; }
    for (int sl = 0; sl < 8; ++sl) {
#pragma unroll
      for (int e = 0; e < 4; ++e) {
        const double v = pv[(t * 8 + sl) * 4 + e];
        const int m = piL[(t * 8 + sl) * 4 + e];
        const bool b0 = BETTER64(v, m, fv[0], fi[0]);
        const bool b1 = BETTER64(v, m, fv[1], fi[1]);
        const bool b2 = BETTER64(v, m, fv[2], fi[2]);
        const bool b3 = BETTER64(v, m, fv[3], fi[3]);
        fv[3] = b2 ? fv[2] : (b3 ? v : fv[3]);
        fi[3] = b2 ? fi[2] : (b3 ? m : fi[3]);
        fv[2] = b1 ? fv[1] : (b2 ? v : fv[2]);
        fi[2] = b1 ? fi[1] : (b2 ? m : fi[2]);
        fv[1] = b0 ? fv[0] : (b1 ? v : fv[1]);
        fi[1] = b0 ? fi[0] : (b1 ? m : fi[1]);
        fv[0] = b0 ? v : fv[0];
        fi[0] = b0 ? m : fi[0];
      }
    }
    int4 o;
    o.x = fi[0]; o.y = fi[1]; o.z = fi[2]; o.w = fi[3];
    *(int4*)(out + ((size_t)b * NQ + qbase + t) * 4) = o;
  }
}

extern "C" void kernel_launch(void* const* d_in, const int* in_sizes, int n_in,
                              void* d_out, int out_size, void* d_ws, size_t ws_size,
                              hipStream_t stream) {
  const float* qry = (const float*)d_in[0];  // (4, 4096, 128) fp32
  const float* img = (const float*)d_in[1];  // (4, 8192, 128) fp32
  int* out = (int*)d_out;                    // (4, 4096, 4) int32

  const size_t qbBytes = (size_t)NBATCH * NQ * KD * sizeof(ushort_t);  // 4 MB
  const size_t ibBytes = (size_t)NBATCH * NM * KD * sizeof(ushort_t);  // 8 MB

  if (ws_size >= qbBytes + ibBytes) {
    ushort_t* qb = (ushort_t*)d_ws;
    int4* ib = (int4*)((char*)d_ws + qbBytes);
    // 524288 query float4-chunks + 524288 image 16B-chunks = 1048576 threads
    wr_cvt<<<4096, 256, 0, stream>>>(qry, img, qb, ib);
    wr_mfma<<<512, 512, 0, stream>>>(qry, img, qb, ib, out);
  } else {
    wr_main<<<NBATCH * (NQ / QT), NTHREADS, 0, stream>>>(qry, img, out);
  }
}

// Round 6
// 144.683 us; speedup vs baseline: 6.1074x; 1.3754x over previous
//
#include <hip/hip_runtime.h>
#include <float.h>
#include <stdint.h>

// WindowRouting: out[b][q][0..3] = indices of top-4 of (Q[b,q,:] . I[b,m,:]) over m.
// Scale dropped (order-preserving).
//
// K0 (wr_cvt): fp32 -> bf16. Query: straight vector convert. Image: per-tile
//   LDS transpose (coalesced fp32 reads -> fragment-linear 16B writes, rows
//   rotated by r*8 ushorts to spread LDS banks). R5's cvt did 32-line gather
//   loads per instr (TA-bound, ~45 us); this is pure-BW (~10 us).
// K1 (wr_mfma): 512 blocks x 512 thr, launch_bounds(512,2). R5's (512,4) was
//   interpreted as min-BLOCKS/CU -> VGPR capped at 64 -> 200 MB scratch spill.
//   (512,2) caps at >=128 under either semantics: bfrag(32)+bufA/B(64)+acc(16)
//   fits, no spill. Wave w owns m-eighth; query frags pinned in VGPRs; image
//   frags fragment-linear with 2-deep double buffer. Scores -> packed keys
//   (low 11 mantissa bits = 2047 - m_local); running top-4 via v_max+3x v_med3,
//   two chains; kh-half merge via SNAPSHOTTED shfl; 32 cand/row -> rank-select
//   top-8 -> fp64 refine vs fp32 originals -> exact top-4 (value desc, idx asc).
// Fallback: fp32 LDS-tiled kernel if ws too small.

#define NBATCH 4
#define NQ 4096
#define NM 8192
#define KD 128

typedef unsigned short ushort_t;
typedef __attribute__((ext_vector_type(8))) short bf16x8;
typedef __attribute__((ext_vector_type(16))) float f32x16;

#define BETTER64(v, i, w, j) (((v) > (w)) || ((v) == (w) && (i) < (j)))

__device__ inline float fmed3(float a, float b, float c) {
#if __has_builtin(__builtin_amdgcn_fmed3f)
  return __builtin_amdgcn_fmed3f(a, b, c);
#else
  return fmaxf(fminf(a, b), fminf(fmaxf(a, b), c));
#endif
}

__device__ inline ushort_t f2bf(float f) {
  unsigned u = __float_as_uint(f);
  u += 0x7fffu + ((u >> 16) & 1u);  // RNE
  return (ushort_t)(u >> 16);
}

// ---------------- K0: convert + swizzle ----------------
// Blocks 0..2047: query, linear bf16 (1 float4 chunk/thread).
// Blocks 2048..3071: image, one 32-m tile each, LDS transpose to
// fragment-linear: chunk n = c*64+l <- m = tile*32 + (l&31), k0 = c*16+(l>>5)*8.
__global__ __launch_bounds__(256) void wr_cvt(const float* __restrict__ qry,
                                              const float* __restrict__ img,
                                              ushort_t* __restrict__ qb,
                                              int4* __restrict__ ib) {
  const int blk = (int)blockIdx.x;
  const int tid = (int)threadIdx.x;
  if (blk < 2048) {
    const int t = blk * 256 + tid;  // 0..524287
    const float4 v = ((const float4*)qry)[t];
    ushort4 o;
    o.x = f2bf(v.x); o.y = f2bf(v.y); o.z = f2bf(v.z); o.w = f2bf(v.w);
    ((ushort4*)qb)[t] = o;
  } else {
    const int tg = blk - 2048;  // 0..1023
    const int b = tg >> 8;
    const int tile = tg & 255;
    __shared__ __align__(16) ushort_t T[32 * 128];
    // coalesced read: thread -> row r, 16 consecutive floats at col seg*16
    {
      const int r = tid >> 3;
      const int seg = tid & 7;
      const float* src = img + ((size_t)(b * NM + tile * 32 + r)) * KD + seg * 16;
      ushort_t tmp[16];
#pragma unroll
      for (int i = 0; i < 4; ++i) {
        const float4 v = ((const float4*)src)[i];
        tmp[i * 4 + 0] = f2bf(v.x);
        tmp[i * 4 + 1] = f2bf(v.y);
        tmp[i * 4 + 2] = f2bf(v.z);
        tmp[i * 4 + 3] = f2bf(v.w);
      }
      // row rotated by r*8 ushorts; 8-ushort chunks never wrap (offsets %8==0)
      const int c0 = (seg * 16 + r * 8) & 127;
      const int c1 = (seg * 16 + 8 + r * 8) & 127;
      *(int4*)&T[r * 128 + c0] = *(const int4*)&tmp[0];
      *(int4*)&T[r * 128 + c1] = *(const int4*)&tmp[8];
    }
    __syncthreads();
    // fragment-linear write: chunks n = tid, tid+256 (64-lane contiguous)
    int4* dstt = ib + ((size_t)b * 256 + tile) * 512;
#pragma unroll
    for (int h = 0; h < 2; ++h) {
      const int n = tid + h * 256;
      const int c = n >> 6;
      const int l = n & 63;
      const int ml = l & 31;
      const int col = (c * 16 + (l >> 5) * 8 + ml * 8) & 127;
      dstt[n] = *(const int4*)&T[ml * 128 + col];
    }
  }
}

// ---------------- K1: MFMA screen + fp64 refine ----------------
__global__ __launch_bounds__(512, 2) void wr_mfma(const float* __restrict__ qry,
                                                  const float* __restrict__ img,
                                                  const ushort_t* __restrict__ qb,
                                                  const int4* __restrict__ ib,
                                                  int* __restrict__ out) {
  const int bid = (int)blockIdx.x;               // 0..511
  const int b = (bid & 7) >> 1;                  // batch pinned to XCD pair
  const int qt = ((bid >> 3) << 1) | (bid & 1);  // 0..127
  const int qbase = qt * 32;

  const int tid = (int)threadIdx.x;
  const int lane = tid & 63;
  const int w = tid >> 6;   // 0..7 -> m-eighth
  const int qc = lane & 31;
  const int kh = lane >> 5;

  const ushort_t* Qb = qb + ((size_t)b * NQ + qbase) * KD;
  const int4* ibc = ib + (size_t)b * 131072;  // this batch's fragment chunks

  // query fragments pinned: B[n=qc][k = c*16 + kh*8 + j]
  bf16x8 bfrag[8];
  {
    const ushort_t* p = Qb + (size_t)qc * KD + kh * 8;
#pragma unroll
    for (int c = 0; c < 8; ++c) bfrag[c] = *(const bf16x8*)(p + c * 16);
  }

  float tva[4], tvb[4];
#pragma unroll
  for (int s = 0; s < 4; ++s) { tva[s] = -FLT_MAX; tvb[s] = -FLT_MAX; }

  bf16x8 bufA[8], bufB[8];

  auto loadTile = [&](bf16x8* buf, int T) {
    const int4* p = ibc + ((((w * 32 + T) << 9)) + lane);
#pragma unroll
    for (int c = 0; c < 8; ++c) buf[c] = *(const bf16x8*)(p + c * 64);
  };

  auto compute = [&](const bf16x8* buf, int vb) {
    f32x16 acc;
#pragma unroll
    for (int r = 0; r < 16; ++r) acc[r] = 0.0f;
#pragma unroll
    for (int c = 0; c < 8; ++c)
      acc = __builtin_amdgcn_mfma_f32_32x32x16_bf16(buf[c], bfrag[c], acc, 0, 0, 0);
#pragma unroll
    for (int r = 0; r < 16; ++r) {
      const int rc = (r & 3) + 8 * (r >> 2);  // inline const
      const unsigned kb =
          (__float_as_uint(acc[r]) & 0xFFFFF800u) | (unsigned)(vb - rc);
      const float key = __uint_as_float(kb);
      if (r & 1) {
        tvb[3] = fmed3(key, tvb[2], tvb[3]);
        tvb[2] = fmed3(key, tvb[1], tvb[2]);
        tvb[1] = fmed3(key, tvb[0], tvb[1]);
        tvb[0] = fmaxf(tvb[0], key);
      } else {
        tva[3] = fmed3(key, tva[2], tva[3]);
        tva[2] = fmed3(key, tva[1], tva[2]);
        tva[1] = fmed3(key, tva[0], tva[1]);
        tva[0] = fmaxf(tva[0], key);
      }
    }
  };

  // vb for tile T: 2047 - 4*kh - 32*T  (always in [1051, 2047] -> 11 bits)
  int vb = 2047 - 4 * kh;
  loadTile(bufA, 0);
  loadTile(bufB, 1);
  for (int T = 0; T < 32; T += 2) {
    compute(bufA, vb);
    if (T + 2 < 32) loadTile(bufA, T + 2);
    compute(bufB, vb - 32);
    if (T + 3 < 32) loadTile(bufB, T + 3);
    vb -= 64;
  }

  // merge chain B into chain A (lane-local)
#pragma unroll
  for (int e = 0; e < 4; ++e) {
    const float key = tvb[e];
    tva[3] = fmed3(key, tva[2], tva[3]);
    tva[2] = fmed3(key, tva[1], tva[2]);
    tva[1] = fmed3(key, tva[0], tva[1]);
    tva[0] = fmaxf(tva[0], key);
  }

  // merge upper kh-half into lower. SNAPSHOT all donor regs first.
  {
    float keys[4];
#pragma unroll
    for (int e = 0; e < 4; ++e) keys[e] = __shfl_down(tva[e], 32, 64);
#pragma unroll
    for (int e = 0; e < 4; ++e) {
      const float key = keys[e];
      tva[3] = fmed3(key, tva[2], tva[3]);
      tva[2] = fmed3(key, tva[1], tva[2]);
      tva[1] = fmed3(key, tva[0], tva[1]);
      tva[0] = fmaxf(tva[0], key);
    }
  }

  // ---- 32 candidates per q-row (8 eighths x 4) ----
  __shared__ float ck[32][33];
  __shared__ int top8[32][8];
  __shared__ double pd[32][8];
  __shared__ int pi[32][8];

  if (kh == 0) {
#pragma unroll
    for (int s = 0; s < 4; ++s) ck[qc][w * 4 + s] = tva[s];
  }
  __syncthreads();

  // ---- rank-select top-8 of 32 packed keys per row (ranks unique) ----
  for (int p = tid; p < 1024; p += 512) {
    const int q = p >> 5;
    const int j = p & 31;
    const float k = ck[q][j];
    int rank = 0;
#pragma unroll 8
    for (int i = 0; i < 32; ++i) {
      const float o = ck[q][i];
      rank += (o > k) || (o == k && i < j);
    }
    if (rank < 8) {
      const unsigned bits = __float_as_uint(k);
      top8[q][rank] = (j >> 2) * 1024 + 2047 - (int)(bits & 0x7FFu);
    }
  }
  __syncthreads();

  // ---- fp64 refine: 8 threads per q-row ----
  if (tid < 256) {
    const int q = tid >> 3;
    const int slot = tid & 7;
    const int m = top8[q][slot];
    const float* qrow = qry + ((size_t)b * NQ + qbase + q) * KD;
    const float* irow = img + ((size_t)b * NM + m) * KD;
    double s0 = 0.0, s1 = 0.0, s2 = 0.0, s3 = 0.0;
#pragma unroll
    for (int k = 0; k < KD; k += 4) {
      const float4 xv = *(const float4*)(qrow + k);
      const float4 yv = *(const float4*)(irow + k);
      s0 = fma((double)xv.x, (double)yv.x, s0);
      s1 = fma((double)xv.y, (double)yv.y, s1);
      s2 = fma((double)xv.z, (double)yv.z, s2);
      s3 = fma((double)xv.w, (double)yv.w, s3);
    }
    pd[q][slot] = (s0 + s1) + (s2 + s3);
    pi[q][slot] = m;
  }
  __syncthreads();

  // ---- exact top-4 of 8 refined, (value desc, index asc) ----
  if (tid < 32) {
    const int q = tid;
    double fv[4];
    int fi[4];
#pragma unroll
    for (int e = 0; e < 4; ++e) { fv[e] = -DBL_MAX; fi[e] = 0x7fffffff; }
    for (int sl = 0; sl < 8; ++sl) {
      const double v = pd[q][sl];
      const int m = pi[q][sl];
      const bool b0 = BETTER64(v, m, fv[0], fi[0]);
      const bool b1 = BETTER64(v, m, fv[1], fi[1]);
      const bool b2 = BETTER64(v, m, fv[2], fi[2]);
      const bool b3 = BETTER64(v, m, fv[3], fi[3]);
      fv[3] = b2 ? fv[2] : (b3 ? v : fv[3]);
      fi[3] = b2 ? fi[2] : (b3 ? m : fi[3]);
      fv[2] = b1 ? fv[1] : (b2 ? v : fv[2]);
      fi[2] = b1 ? fi[1] : (b2 ? m : fi[2]);
      fv[1] = b0 ? fv[0] : (b1 ? v : fv[1]);
      fi[1] = b0 ? fi[0] : (b1 ? m : fi[1]);
      fv[0] = b0 ? v : fv[0];
      fi[0] = b0 ? m : fi[0];
    }
    int4 o;
    o.x = fi[0]; o.y = fi[1]; o.z = fi[2]; o.w = fi[3];
    *(int4*)(out + ((size_t)b * NQ + qbase + q) * 4) = o;
  }
}

// ---------------- Fallback: fp32 LDS-tiled kernel (ws too small) ----------------
#define QT 64
#define MT 128
#define KC 64
#define NTHREADS 512

__global__ __launch_bounds__(NTHREADS) void wr_main(const float* __restrict__ qry,
                                                    const float* __restrict__ img,
                                                    int* __restrict__ out) {
  __shared__ __align__(16) float A_lds[KD * QT];
  __shared__ __align__(16) float B_lds[KC * MT];

  const int t = (int)threadIdx.x;
  const int b = (int)blockIdx.x >> 6;
  const int qbase = ((int)blockIdx.x & 63) * QT;

  const float* qp = qry + ((size_t)b * NQ + qbase) * KD;
  const float* ip = img + (size_t)b * NM * KD;

  {
    const int r = t >> 3;
    const int kc = t & 7;
    const float* src = qp + (size_t)r * KD;
#pragma unroll
    for (int i = 0; i < 4; ++i) {
      const int k0 = kc * 4 + i * 32;
      const float4 v = *(const float4*)(src + k0);
      A_lds[(k0 + 0) * QT + r] = v.x;
      A_lds[(k0 + 1) * QT + r] = v.y;
      A_lds[(k0 + 2) * QT + r] = v.z;
      A_lds[(k0 + 3) * QT + r] = v.w;
    }
  }

  const int qi = t >> 5;
  const int mi = t & 31;

  float tv[4][4];
  int ti[4][4];
#pragma unroll
  for (int j = 0; j < 4; ++j)
#pragma unroll
    for (int s = 0; s < 4; ++s) { tv[j][s] = -FLT_MAX; ti[j][s] = 0x7fffffff; }

  for (int tile = 0; tile < NM / MT; ++tile) {
    const int mbase = tile * MT;
    float acc[4][4];
#pragma unroll
    for (int j = 0; j < 4; ++j)
#pragma unroll
      for (int s = 0; s < 4; ++s) acc[j][s] = 0.0f;

    for (int kb = 0; kb < KD; kb += KC) {
      __syncthreads();
      {
        const int r = t >> 2;
        const int kc = t & 3;
        const float* src = ip + (size_t)(mbase + r) * KD + kb;
#pragma unroll
        for (int i = 0; i < 4; ++i) {
          const int k0 = kc * 4 + i * 16;
          const float4 v = *(const float4*)(src + k0);
          B_lds[(k0 + 0) * MT + r] = v.x;
          B_lds[(k0 + 1) * MT + r] = v.y;
          B_lds[(k0 + 2) * MT + r] = v.z;
          B_lds[(k0 + 3) * MT + r] = v.w;
        }
      }
      __syncthreads();

#pragma unroll 8
      for (int k = 0; k < KC; ++k) {
        const float4 av = *(const float4*)&A_lds[(kb + k) * QT + qi * 4];
        const float4 bv = *(const float4*)&B_lds[k * MT + mi * 4];
        acc[0][0] = fmaf(av.x, bv.x, acc[0][0]);
        acc[0][1] = fmaf(av.x, bv.y, acc[0][1]);
        acc[0][2] = fmaf(av.x, bv.z, acc[0][2]);
        acc[0][3] = fmaf(av.x, bv.w, acc[0][3]);
        acc[1][0] = fmaf(av.y, bv.x, acc[1][0]);
        acc[1][1] = fmaf(av.y, bv.y, acc[1][1]);
        acc[1][2] = fmaf(av.y, bv.z, acc[1][2]);
        acc[1][3] = fmaf(av.y, bv.w, acc[1][3]);
        acc[2][0] = fmaf(av.z, bv.x, acc[2][0]);
        acc[2][1] = fmaf(av.z, bv.y, acc[2][1]);
        acc[2][2] = fmaf(av.z, bv.z, acc[2][2]);
        acc[2][3] = fmaf(av.z, bv.w, acc[2][3]);
        acc[3][0] = fmaf(av.w, bv.x, acc[3][0]);
        acc[3][1] = fmaf(av.w, bv.y, acc[3][1]);
        acc[3][2] = fmaf(av.w, bv.z, acc[3][2]);
        acc[3][3] = fmaf(av.w, bv.w, acc[3][3]);
      }
    }

#pragma unroll
    for (int j = 0; j < 4; ++j) {
#pragma unroll
      for (int s = 0; s < 4; ++s) {
        const float v = acc[j][s];
        const int m = mbase + mi * 4 + s;
        const bool b0 = v > tv[j][0];
        const bool b1 = v > tv[j][1];
        const bool b2 = v > tv[j][2];
        const bool b3 = v > tv[j][3];
        tv[j][3] = b2 ? tv[j][2] : (b3 ? v : tv[j][3]);
        ti[j][3] = b2 ? ti[j][2] : (b3 ? m : ti[j][3]);
        tv[j][2] = b1 ? tv[j][1] : (b2 ? v : tv[j][2]);
        ti[j][2] = b1 ? ti[j][1] : (b2 ? m : ti[j][2]);
        tv[j][1] = b0 ? tv[j][0] : (b1 ? v : tv[j][1]);
        ti[j][1] = b0 ? ti[j][0] : (b1 ? m : ti[j][1]);
        tv[j][0] = b0 ? v : tv[j][0];
        ti[j][0] = b0 ? m : ti[j][0];
      }
    }
  }

  __syncthreads();
  int* idx_lds = (int*)B_lds;
#pragma unroll
  for (int j = 0; j < 4; ++j)
#pragma unroll
    for (int s = 0; s < 4; ++s)
      idx_lds[(qi * 4 + j) * 128 + mi * 4 + s] = ti[j][s];
  __syncthreads();

  double* pv = (double*)A_lds;
  int* piL = (int*)(A_lds + 4096);
  {
    const int r = t >> 3;
    const int slot = t & 7;
    const float* qrow = qp + (size_t)r * KD;
    double bv[4];
    int bi[4];
#pragma unroll
    for (int e = 0; e < 4; ++e) { bv[e] = -DBL_MAX; bi[e] = 0x7fffffff; }

    for (int c = 0; c < 16; ++c) {
      const int m = idx_lds[r * 128 + slot * 16 + c];
      const float* irow = ip + (size_t)m * KD;
      double s0 = 0.0, s1 = 0.0, s2 = 0.0, s3 = 0.0;
#pragma unroll
      for (int k = 0; k < KD; k += 4) {
        const float4 xv = *(const float4*)(qrow + k);
        const float4 yv = *(const float4*)(irow + k);
        s0 = fma((double)xv.x, (double)yv.x, s0);
        s1 = fma((double)xv.y, (double)yv.y, s1);
        s2 = fma((double)xv.z, (double)yv.z, s2);
        s3 = fma((double)xv.w, (double)yv.w, s3);
      }
      const double v = (s0 + s1) + (s2 + s3);
      const bool b0 = BETTER64(v, m, bv[0], bi[0]);
      const bool b1 = BETTER64(v, m, bv[1], bi[1]);
      const bool b2 = BETTER64(v, m, bv[2], bi[2]);
      const bool b3 = BETTER64(v, m, bv[3], bi[3]);
      bv[3] = b2 ? bv[2] : (b3 ? v : bv[3]);
      bi[3] = b2 ? bi[2] : (b3 ? m : bi[3]);
      bv[2] = b1 ? bv[1] : (b2 ? v : bv[2]);
      bi[2] = b1 ? bi[1] : (b2 ? m : bi[2]);
      bv[1] = b0 ? bv[0] : (b1 ? v : bv[1]);
      bi[1] = b0 ? bi[0] : (b1 ? m : bi[1]);
      bv[0] = b0 ? v : bv[0];
      bi[0] = b0 ? m : bi[0];
    }
#pragma unroll
    for (int e = 0; e < 4; ++e) {
      pv[t * 4 + e] = bv[e];
      piL[t * 4 + e] = bi[e];
    }
  }
  __syncthreads();

  if (t < QT) {
    double fv[4];
    int fi[4];
#pragma unroll
    for (int e = 0; e < 4; ++e) { fv[e] = -DBL_MAX; fi[e] = 0x7fffffff; }
    for (int sl = 0; sl < 8; ++sl) {
#pragma unroll
      for (int e = 0; e < 4; ++e) {
        const double v = pv[(t * 8 + sl) * 4 + e];
        const int m = piL[(t * 8 + sl) * 4 + e];
        const bool b0 = BETTER64(v, m, fv[0], fi[0]);
        const bool b1 = BETTER64(v, m, fv[1], fi[1]);
        const bool b2 = BETTER64(v, m, fv[2], fi[2]);
        const bool b3 = BETTER64(v, m, fv[3], fi[3]);
        fv[3] = b2 ? fv[2] : (b3 ? v : fv[3]);
        fi[3] = b2 ? fi[2] : (b3 ? m : fi[3]);
        fv[2] = b1 ? fv[1] : (b2 ? v : fv[2]);
        fi[2] = b1 ? fi[1] : (b2 ? m : fi[2]);
        fv[1] = b0 ? fv[0] : (b1 ? v : fv[1]);
        fi[1] = b0 ? fi[0] : (b1 ? m : fi[1]);
        fv[0] = b0 ? v : fv[0];
        fi[0] = b0 ? m : fi[0];
      }
    }
    int4 o;
    o.x = fi[0]; o.y = fi[1]; o.z = fi[2]; o.w = fi[3];
    *(int4*)(out + ((size_t)b * NQ + qbase + t) * 4) = o;
  }
}

extern "C" void kernel_launch(void* const* d_in, const int* in_sizes, int n_in,
                              void* d_out, int out_size, void* d_ws, size_t ws_size,
                              hipStream_t stream) {
  const float* qry = (const float*)d_in[0];  // (4, 4096, 128) fp32
  const float* img = (const float*)d_in[1];  // (4, 8192, 128) fp32
  int* out = (int*)d_out;                    // (4, 4096, 4) int32

  const size_t qbBytes = (size_t)NBATCH * NQ * KD * sizeof(ushort_t);  // 4 MB
  const size_t ibBytes = (size_t)NBATCH * NM * KD * sizeof(ushort_t);  // 8 MB

  if (ws_size >= qbBytes + ibBytes) {
    ushort_t* qb = (ushort_t*)d_ws;
    int4* ib = (int4*)((char*)d_ws + qbBytes);
    // 2048 query blocks + 1024 image-tile blocks
    wr_cvt<<<3072, 256, 0, stream>>>(qry, img, qb, ib);
    wr_mfma<<<512, 512, 0, stream>>>(qry, img, qb, ib, out);
  } else {
    wr_main<<<NBATCH * (NQ / QT), NTHREADS, 0, stream>>>(qry, img, out);
  }
}

// Round 7
// 138.887 us; speedup vs baseline: 6.3622x; 1.0417x over previous
//
#include <hip/hip_runtime.h>
#include <float.h>
#include <stdint.h>

// WindowRouting: out[b][q][0..3] = indices of top-4 of (Q[b,q,:] . I[b,m,:]) over m.
// Scale dropped (order-preserving).
//
// K0 (wr_cvt): fp32 -> bf16. Query linear; image LDS-transposed per 32-m tile
//   into 16x16x32-fragment-linear half-tiles (16 m x 128 k = 256 x 16B chunks:
//   chunk n: kstep=(n>>6)&3, lane=n&63 -> m=ht*16+(l&15), k=kstep*32+(l>>4)*8).
// K1 (wr_mfma): 512 blocks x 512 thr. Block = 32 q x all m; wave w = m-eighth
//   (64 half-tiles of 16 m). R6 lesson: 32x32 shape needed ~140 VGPR+AGPR ->
//   2 waves/EU (occupancy 20%). This round: 16x16x32 MFMA, 3-deep rotating
//   16-reg half-tile buffers, acc 8, two 4-reg chains -> ~113 regs -> 4
//   waves/EU. Scores -> packed keys (low 11 bits = 2047 - m_local); running
//   top-4 via v_max+3x v_med3; quad-tree shfl merge (snapshot-first);
//   32 cand/row -> rank-select top-8 -> fp64 refine vs fp32 originals ->
//   exact top-4 (value desc, index asc).
// Fallback: fp32 LDS-tiled kernel if ws too small.

#define NBATCH 4
#define NQ 4096
#define NM 8192
#define KD 128

typedef unsigned short ushort_t;
typedef __attribute__((ext_vector_type(8))) short bf16x8;
typedef __attribute__((ext_vector_type(4))) float f32x4;

#define BETTER64(v, i, w, j) (((v) > (w)) || ((v) == (w) && (i) < (j)))

__device__ inline float fmed3(float a, float b, float c) {
#if __has_builtin(__builtin_amdgcn_fmed3f)
  return __builtin_amdgcn_fmed3f(a, b, c);
#else
  return fmaxf(fminf(a, b), fminf(fmaxf(a, b), c));
#endif
}

__device__ inline ushort_t f2bf(float f) {
  unsigned u = __float_as_uint(f);
  u += 0x7fffu + ((u >> 16) & 1u);  // RNE
  return (ushort_t)(u >> 16);
}

// ---------------- K0: convert + swizzle ----------------
__global__ __launch_bounds__(256) void wr_cvt(const float* __restrict__ qry,
                                              const float* __restrict__ img,
                                              ushort_t* __restrict__ qb,
                                              int4* __restrict__ ib) {
  const int blk = (int)blockIdx.x;
  const int tid = (int)threadIdx.x;
  if (blk < 2048) {
    const int t = blk * 256 + tid;  // 0..524287
    const float4 v = ((const float4*)qry)[t];
    ushort4 o;
    o.x = f2bf(v.x); o.y = f2bf(v.y); o.z = f2bf(v.z); o.w = f2bf(v.w);
    ((ushort4*)qb)[t] = o;
  } else {
    const int tg = blk - 2048;  // 0..1023 : one 32-m tile (= 2 half-tiles)
    const int b = tg >> 8;
    const int tile = tg & 255;
    __shared__ __align__(16) ushort_t T[32 * 128];
    // coalesced read: row r, 16 consecutive floats at col seg*16; rows rotated
    {
      const int r = tid >> 3;
      const int seg = tid & 7;
      const float* src = img + ((size_t)(b * NM + tile * 32 + r)) * KD + seg * 16;
      ushort_t tmp[16];
#pragma unroll
      for (int i = 0; i < 4; ++i) {
        const float4 v = ((const float4*)src)[i];
        tmp[i * 4 + 0] = f2bf(v.x);
        tmp[i * 4 + 1] = f2bf(v.y);
        tmp[i * 4 + 2] = f2bf(v.z);
        tmp[i * 4 + 3] = f2bf(v.w);
      }
      const int c0 = (seg * 16 + r * 8) & 127;
      const int c1 = (seg * 16 + 8 + r * 8) & 127;
      *(int4*)&T[r * 128 + c0] = *(const int4*)&tmp[0];
      *(int4*)&T[r * 128 + c1] = *(const int4*)&tmp[8];
    }
    __syncthreads();
    // fragment-linear write (16x16x32 layout), chunks n = tid, tid+256
    int4* dstt = ib + ((size_t)b * 256 + tile) * 512;
#pragma unroll
    for (int h = 0; h < 2; ++h) {
      const int n = tid + h * 256;
      const int l = n & 63;
      const int ks = (n >> 6) & 3;
      const int htl = n >> 8;                 // half-tile within this 32-m tile
      const int row = htl * 16 + (l & 15);    // m within tile
      const int col = ks * 32 + (l >> 4) * 8; // k
      dstt[n] = *(const int4*)&T[row * 128 + ((col + row * 8) & 127)];
    }
  }
}

// ---------------- K1: MFMA screen + fp64 refine ----------------
__global__ __launch_bounds__(512, 2) void wr_mfma(const float* __restrict__ qry,
                                                  const float* __restrict__ img,
                                                  const ushort_t* __restrict__ qb,
                                                  const int4* __restrict__ ib,
                                                  int* __restrict__ out) {
  const int bid = (int)blockIdx.x;               // 0..511
  const int b = (bid & 7) >> 1;                  // batch pinned to XCD pair
  const int qt = ((bid >> 3) << 1) | (bid & 1);  // 0..127
  const int qbase = qt * 32;

  const int tid = (int)threadIdx.x;
  const int lane = tid & 63;
  const int w = tid >> 6;        // 0..7 -> m-eighth (64 half-tiles)
  const int q15 = lane & 15;
  const int quad = lane >> 4;    // 0..3

  const ushort_t* Qb = qb + ((size_t)b * NQ + qbase) * KD;
  const int4* ibc = ib + (size_t)b * 131072;

  // query fragments pinned: B[n=q15][k = ks*32 + quad*8 + j], two q-halves
  bf16x8 bfrag0[4], bfrag1[4];
#pragma unroll
  for (int ks = 0; ks < 4; ++ks) {
    bfrag0[ks] = *(const bf16x8*)(Qb + (size_t)q15 * KD + ks * 32 + quad * 8);
    bfrag1[ks] = *(const bf16x8*)(Qb + (size_t)(16 + q15) * KD + ks * 32 + quad * 8);
  }

  float tq0[4], tq1[4];
#pragma unroll
  for (int s = 0; s < 4; ++s) { tq0[s] = -FLT_MAX; tq1[s] = -FLT_MAX; }

  bf16x8 B0[4], B1[4], B2[4];

  auto loadH = [&](bf16x8* R, int h) {
    const int4* p = ibc + (((w * 64 + h) << 8) + lane);
#pragma unroll
    for (int ks = 0; ks < 4; ++ks) R[ks] = *(const bf16x8*)(p + ks * 64);
  };

  int hl = 3;
  int vb = 2047 - 4 * quad;  // key base; m_local = 16*ht + 4*quad + r

  auto step = [&](bf16x8* R) {
    f32x4 a0 = {0.f, 0.f, 0.f, 0.f}, a1 = {0.f, 0.f, 0.f, 0.f};
#pragma unroll
    for (int ks = 0; ks < 4; ++ks) {
      a0 = __builtin_amdgcn_mfma_f32_16x16x32_bf16(R[ks], bfrag0[ks], a0, 0, 0, 0);
      a1 = __builtin_amdgcn_mfma_f32_16x16x32_bf16(R[ks], bfrag1[ks], a1, 0, 0, 0);
    }
    if (hl < 64) loadH(R, hl);  // refill this buffer, used again 3 steps later
    ++hl;
#pragma unroll
    for (int r = 0; r < 4; ++r) {
      const unsigned kr = (unsigned)(vb - r);
      const float ka =
          __uint_as_float((__float_as_uint(a0[r]) & 0xFFFFF800u) | kr);
      tq0[3] = fmed3(ka, tq0[2], tq0[3]);
      tq0[2] = fmed3(ka, tq0[1], tq0[2]);
      tq0[1] = fmed3(ka, tq0[0], tq0[1]);
      tq0[0] = fmaxf(tq0[0], ka);
      const float kb =
          __uint_as_float((__float_as_uint(a1[r]) & 0xFFFFF800u) | kr);
      tq1[3] = fmed3(kb, tq1[2], tq1[3]);
      tq1[2] = fmed3(kb, tq1[1], tq1[2]);
      tq1[1] = fmed3(kb, tq1[0], tq1[1]);
      tq1[0] = fmaxf(tq1[0], kb);
    }
    vb -= 16;
  };

  loadH(B0, 0);
  loadH(B1, 1);
  loadH(B2, 2);
  for (int g = 0; g < 21; ++g) { step(B0); step(B1); step(B2); }
  step(B0);  // half-tile 63

  // ---- quad-tree merge (snapshot donor regs BEFORE mutating — R4 lesson) ----
  {
    float k4[4];
#pragma unroll
    for (int e = 0; e < 4; ++e) k4[e] = __shfl_down(tq0[e], 32, 64);
#pragma unroll
    for (int e = 0; e < 4; ++e) {
      const float k = k4[e];
      tq0[3] = fmed3(k, tq0[2], tq0[3]);
      tq0[2] = fmed3(k, tq0[1], tq0[2]);
      tq0[1] = fmed3(k, tq0[0], tq0[1]);
      tq0[0] = fmaxf(tq0[0], k);
    }
#pragma unroll
    for (int e = 0; e < 4; ++e) k4[e] = __shfl_down(tq0[e], 16, 64);
#pragma unroll
    for (int e = 0; e < 4; ++e) {
      const float k = k4[e];
      tq0[3] = fmed3(k, tq0[2], tq0[3]);
      tq0[2] = fmed3(k, tq0[1], tq0[2]);
      tq0[1] = fmed3(k, tq0[0], tq0[1]);
      tq0[0] = fmaxf(tq0[0], k);
    }
#pragma unroll
    for (int e = 0; e < 4; ++e) k4[e] = __shfl_down(tq1[e], 32, 64);
#pragma unroll
    for (int e = 0; e < 4; ++e) {
      const float k = k4[e];
      tq1[3] = fmed3(k, tq1[2], tq1[3]);
      tq1[2] = fmed3(k, tq1[1], tq1[2]);
      tq1[1] = fmed3(k, tq1[0], tq1[1]);
      tq1[0] = fmaxf(tq1[0], k);
    }
#pragma unroll
    for (int e = 0; e < 4; ++e) k4[e] = __shfl_down(tq1[e], 16, 64);
#pragma unroll
    for (int e = 0; e < 4; ++e) {
      const float k = k4[e];
      tq1[3] = fmed3(k, tq1[2], tq1[3]);
      tq1[2] = fmed3(k, tq1[1], tq1[2]);
      tq1[1] = fmed3(k, tq1[0], tq1[1]);
      tq1[0] = fmaxf(tq1[0], k);
    }
  }

  // ---- 32 candidates per q-row (8 eighths x 4) ----
  __shared__ float ck[32][33];
  __shared__ int top8[32][8];
  __shared__ double pd[32][8];
  __shared__ int pi[32][8];

  if (lane < 16) {
#pragma unroll
    for (int s = 0; s < 4; ++s) {
      ck[q15][w * 4 + s] = tq0[s];
      ck[16 + q15][w * 4 + s] = tq1[s];
    }
  }
  __syncthreads();

  // ---- rank-select top-8 of 32 packed keys per row (ranks unique) ----
  for (int p = tid; p < 1024; p += 512) {
    const int q = p >> 5;
    const int j = p & 31;
    const float k = ck[q][j];
    int rank = 0;
#pragma unroll 8
    for (int i = 0; i < 32; ++i) {
      const float o = ck[q][i];
      rank += (o > k) || (o == k && i < j);
    }
    if (rank < 8) {
      const unsigned bits = __float_as_uint(k);
      top8[q][rank] = (j >> 2) * 1024 + 2047 - (int)(bits & 0x7FFu);
    }
  }
  __syncthreads();

  // ---- fp64 refine: 8 threads per q-row ----
  if (tid < 256) {
    const int q = tid >> 3;
    const int slot = tid & 7;
    const int m = top8[q][slot];
    const float* qrow = qry + ((size_t)b * NQ + qbase + q) * KD;
    const float* irow = img + ((size_t)b * NM + m) * KD;
    double s0 = 0.0, s1 = 0.0, s2 = 0.0, s3 = 0.0;
#pragma unroll
    for (int k = 0; k < KD; k += 4) {
      const float4 xv = *(const float4*)(qrow + k);
      const float4 yv = *(const float4*)(irow + k);
      s0 = fma((double)xv.x, (double)yv.x, s0);
      s1 = fma((double)xv.y, (double)yv.y, s1);
      s2 = fma((double)xv.z, (double)yv.z, s2);
      s3 = fma((double)xv.w, (double)yv.w, s3);
    }
    pd[q][slot] = (s0 + s1) + (s2 + s3);
    pi[q][slot] = m;
  }
  __syncthreads();

  // ---- exact top-4 of 8 refined, (value desc, index asc) ----
  if (tid < 32) {
    const int q = tid;
    double fv[4];
    int fi[4];
#pragma unroll
    for (int e = 0; e < 4; ++e) { fv[e] = -DBL_MAX; fi[e] = 0x7fffffff; }
    for (int sl = 0; sl < 8; ++sl) {
      const double v = pd[q][sl];
      const int m = pi[q][sl];
      const bool b0 = BETTER64(v, m, fv[0], fi[0]);
      const bool b1 = BETTER64(v, m, fv[1], fi[1]);
      const bool b2 = BETTER64(v, m, fv[2], fi[2]);
      const bool b3 = BETTER64(v, m, fv[3], fi[3]);
      fv[3] = b2 ? fv[2] : (b3 ? v : fv[3]);
      fi[3] = b2 ? fi[2] : (b3 ? m : fi[3]);
      fv[2] = b1 ? fv[1] : (b2 ? v : fv[2]);
      fi[2] = b1 ? fi[1] : (b2 ? m : fi[2]);
      fv[1] = b0 ? fv[0] : (b1 ? v : fv[1]);
      fi[1] = b0 ? fi[0] : (b1 ? m : fi[1]);
      fv[0] = b0 ? v : fv[0];
      fi[0] = b0 ? m : fi[0];
    }
    int4 o;
    o.x = fi[0]; o.y = fi[1]; o.z = fi[2]; o.w = fi[3];
    *(int4*)(out + ((size_t)b * NQ + qbase + q) * 4) = o;
  }
}

// ---------------- Fallback: fp32 LDS-tiled kernel (ws too small) ----------------
#define QT 64
#define MT 128
#define KC 64
#define NTHREADS 512

__global__ __launch_bounds__(NTHREADS) void wr_main(const float* __restrict__ qry,
                                                    const float* __restrict__ img,
                                                    int* __restrict__ out) {
  __shared__ __align__(16) float A_lds[KD * QT];
  __shared__ __align__(16) float B_lds[KC * MT];

  const int t = (int)threadIdx.x;
  const int b = (int)blockIdx.x >> 6;
  const int qbase = ((int)blockIdx.x & 63) * QT;

  const float* qp = qry + ((size_t)b * NQ + qbase) * KD;
  const float* ip = img + (size_t)b * NM * KD;

  {
    const int r = t >> 3;
    const int kc = t & 7;
    const float* src = qp + (size_t)r * KD;
#pragma unroll
    for (int i = 0; i < 4; ++i) {
      const int k0 = kc * 4 + i * 32;
      const float4 v = *(const float4*)(src + k0);
      A_lds[(k0 + 0) * QT + r] = v.x;
      A_lds[(k0 + 1) * QT + r] = v.y;
      A_lds[(k0 + 2) * QT + r] = v.z;
      A_lds[(k0 + 3) * QT + r] = v.w;
    }
  }

  const int qi = t >> 5;
  const int mi = t & 31;

  float tv[4][4];
  int ti[4][4];
#pragma unroll
  for (int j = 0; j < 4; ++j)
#pragma unroll
    for (int s = 0; s < 4; ++s) { tv[j][s] = -FLT_MAX; ti[j][s] = 0x7fffffff; }

  for (int tile = 0; tile < NM / MT; ++tile) {
    const int mbase = tile * MT;
    float acc[4][4];
#pragma unroll
    for (int j = 0; j < 4; ++j)
#pragma unroll
      for (int s = 0; s < 4; ++s) acc[j][s] = 0.0f;

    for (int kb = 0; kb < KD; kb += KC) {
      __syncthreads();
      {
        const int r = t >> 2;
        const int kc = t & 3;
        const float* src = ip + (size_t)(mbase + r) * KD + kb;
#pragma unroll
        for (int i = 0; i < 4; ++i) {
          const int k0 = kc * 4 + i * 16;
          const float4 v = *(const float4*)(src + k0);
          B_lds[(k0 + 0) * MT + r] = v.x;
          B_lds[(k0 + 1) * MT + r] = v.y;
          B_lds[(k0 + 2) * MT + r] = v.z;
          B_lds[(k0 + 3) * MT + r] = v.w;
        }
      }
      __syncthreads();

#pragma unroll 8
      for (int k = 0; k < KC; ++k) {
        const float4 av = *(const float4*)&A_lds[(kb + k) * QT + qi * 4];
        const float4 bv = *(const float4*)&B_lds[k * MT + mi * 4];
        acc[0][0] = fmaf(av.x, bv.x, acc[0][0]);
        acc[0][1] = fmaf(av.x, bv.y, acc[0][1]);
        acc[0][2] = fmaf(av.x, bv.z, acc[0][2]);
        acc[0][3] = fmaf(av.x, bv.w, acc[0][3]);
        acc[1][0] = fmaf(av.y, bv.x, acc[1][0]);
        acc[1][1] = fmaf(av.y, bv.y, acc[1][1]);
        acc[1][2] = fmaf(av.y, bv.z, acc[1][2]);
        acc[1][3] = fmaf(av.y, bv.w, acc[1][3]);
        acc[2][0] = fmaf(av.z, bv.x, acc[2][0]);
        acc[2][1] = fmaf(av.z, bv.y, acc[2][1]);
        acc[2][2] = fmaf(av.z, bv.z, acc[2][2]);
        acc[2][3] = fmaf(av.z, bv.w, acc[2][3]);
        acc[3][0] = fmaf(av.w, bv.x, acc[3][0]);
        acc[3][1] = fmaf(av.w, bv.y, acc[3][1]);
        acc[3][2] = fmaf(av.w, bv.z, acc[3][2]);
        acc[3][3] = fmaf(av.w, bv.w, acc[3][3]);
      }
    }

#pragma unroll
    for (int j = 0; j < 4; ++j) {
#pragma unroll
      for (int s = 0; s < 4; ++s) {
        const float v = acc[j][s];
        const int m = mbase + mi * 4 + s;
        const bool b0 = v > tv[j][0];
        const bool b1 = v > tv[j][1];
        const bool b2 = v > tv[j][2];
        const bool b3 = v > tv[j][3];
        tv[j][3] = b2 ? tv[j][2] : (b3 ? v : tv[j][3]);
        ti[j][3] = b2 ? ti[j][2] : (b3 ? m : ti[j][3]);
        tv[j][2] = b1 ? tv[j][1] : (b2 ? v : tv[j][2]);
        ti[j][2] = b1 ? ti[j][1] : (b2 ? m : ti[j][2]);
        tv[j][1] = b0 ? tv[j][0] : (b1 ? v : tv[j][1]);
        ti[j][1] = b0 ? ti[j][0] : (b1 ? m : ti[j][1]);
        tv[j][0] = b0 ? v : tv[j][0];
        ti[j][0] = b0 ? m : ti[j][0];
      }
    }
  }

  __syncthreads();
  int* idx_lds = (int*)B_lds;
#pragma unroll
  for (int j = 0; j < 4; ++j)
#pragma unroll
    for (int s = 0; s < 4; ++s)
      idx_lds[(qi * 4 + j) * 128 + mi * 4 + s] = ti[j][s];
  __syncthreads();

  double* pv = (double*)A_lds;
  int* piL = (int*)(A_lds + 4096);
  {
    const int r = t >> 3;
    const int slot = t & 7;
    const float* qrow = qp + (size_t)r * KD;
    double bv[4];
    int bi[4];
#pragma unroll
    for (int e = 0; e < 4; ++e) { bv[e] = -DBL_MAX; bi[e] = 0x7fffffff; }

    for (int c = 0; c < 16; ++c) {
      const int m = idx_lds[r * 128 + slot * 16 + c];
      const float* irow = ip + (size_t)m * KD;
      double s0 = 0.0, s1 = 0.0, s2 = 0.0, s3 = 0.0;
#pragma unroll
      for (int k = 0; k < KD; k += 4) {
        const float4 xv = *(const float4*)(qrow + k);
        const float4 yv = *(const float4*)(irow + k);
        s0 = fma((double)xv.x, (double)yv.x, s0);
        s1 = fma((double)xv.y, (double)yv.y, s1);
        s2 = fma((double)xv.z, (double)yv.z, s2);
        s3 = fma((double)xv.w, (double)yv.w, s3);
      }
      const double v = (s0 + s1) + (s2 + s3);
      const bool b0 = BETTER64(v, m, bv[0], bi[0]);
      const bool b1 = BETTER64(v, m, bv[1], bi[1]);
      const bool b2 = BETTER64(v, m, bv[2], bi[2]);
      const bool b3 = BETTER64(v, m, bv[3], bi[3]);
      bv[3] = b2 ? bv[2] : (b3 ? v : bv[3]);
      bi[3] = b2 ? bi[2] : (b3 ? m : bi[3]);
      bv[2] = b1 ? bv[1] : (b2 ? v : bv[2]);
      bi[2] = b1 ? bi[1] : (b2 ? m : bi[2]);
      bv[1] = b0 ? bv[0] : (b1 ? v : bv[1]);
      bi[1] = b0 ? bi[0] : (b1 ? m : bi[1]);
      bv[0] = b0 ? v : bv[0];
      bi[0] = b0 ? m : bi[0];
    }
#pragma unroll
    for (int e = 0; e < 4; ++e) {
      pv[t * 4 + e] = bv[e];
      piL[t * 4 + e] = bi[e];
    }
  }
  __syncthreads();

  if (t < QT) {
    double fv[4];
    int fi[4];
#pragma unroll
    for (int e = 0; e < 4; ++e) { fv[e] = -DBL_MAX; fi[e] = 0x7fffffff; }
    for (int sl = 0; sl < 8; ++sl) {
#pragma unroll
      for (int e = 0; e < 4; ++e) {
        const double v = pv[(t * 8 + sl) * 4 + e];
        const int m = piL[(t * 8 + sl) * 4 + e];
        const bool b0 = BETTER64(v, m, fv[0], fi[0]);
        const bool b1 = BETTER64(v, m, fv[1], fi[1]);
        const bool b2 = BETTER64(v, m, fv[2], fi[2]);
        const bool b3 = BETTER64(v, m, fv[3], fi[3]);
        fv[3] = b2 ? fv[2] : (b3 ? v : fv[3]);
        fi[3] = b2 ? fi[2] : (b3 ? m : fi[3]);
        fv[2] = b1 ? fv[1] : (b2 ? v : fv[2]);
        fi[2] = b1 ? fi[1] : (b2 ? m : fi[2]);
        fv[1] = b0 ? fv[0] : (b1 ? v : fv[1]);
        fi[1] = b0 ? fi[0] : (b1 ? m : fi[1]);
        fv[0] = b0 ? v : fv[0];
        fi[0] = b0 ? m : fi[0];
      }
    }
    int4 o;
    o.x = fi[0]; o.y = fi[1]; o.z = fi[2]; o.w = fi[3];
    *(int4*)(out + ((size_t)b * NQ + qbase + t) * 4) = o;
  }
}

extern "C" void kernel_launch(void* const* d_in, const int* in_sizes, int n_in,
                              void* d_out, int out_size, void* d_ws, size_t ws_size,
                              hipStream_t stream) {
  const float* qry = (const float*)d_in[0];  // (4, 4096, 128) fp32
  const float* img = (const float*)d_in[1];  // (4, 8192, 128) fp32
  int* out = (int*)d_out;                    // (4, 4096, 4) int32

  const size_t qbBytes = (size_t)NBATCH * NQ * KD * sizeof(ushort_t);  // 4 MB
  const size_t ibBytes = (size_t)NBATCH * NM * KD * sizeof(ushort_t);  // 8 MB

  if (ws_size >= qbBytes + ibBytes) {
    ushort_t* qb = (ushort_t*)d_ws;
    int4* ib = (int4*)((char*)d_ws + qbBytes);
    wr_cvt<<<3072, 256, 0, stream>>>(qry, img, qb, ib);
    wr_mfma<<<512, 512, 0, stream>>>(qry, img, qb, ib, out);
  } else {
    wr_main<<<NBATCH * (NQ / QT), NTHREADS, 0, stream>>>(qry, img, out);
  }
}

// Round 8
// 133.032 us; speedup vs baseline: 6.6423x; 1.0440x over previous
//
#include <hip/hip_runtime.h>
#include <float.h>
#include <stdint.h>

// WindowRouting: out[b][q][0..3] = indices of top-4 of (Q[b,q,:] . I[b,m,:]) over m.
// Scale dropped (order-preserving).
//
// K0 (wr_cvt): fp32 -> bf16. Query linear; image LDS-transposed per 32-m tile
//   into 16x16x32-fragment-linear half-tiles (unchanged from R7).
// K1 (wr_mfma): 256 blocks x 512 thr, launch_bounds(512,1). Block = 64 q x all
//   8192 m. Wave w = m-eighth (64 half-tiles of 16 m). q_per_wave = 64 (4
//   q-strips of 16, bfrag pinned in 64 VGPRs) -> each 4KB half-tile load feeds
//   16 MFMAs (R7: 8) -> L1 issued-bytes floor halves to ~13.5 us/CU. 3-deep
//   rotating 16-reg image buffers; all 16 MFMAs consume R before refill.
//   Scores -> packed keys (low 11 bits = 2047 - m_local, m_local < 1024);
//   running top-4 via v_max+3x v_med3, one chain per strip; quad-tree shfl
//   merge (snapshot-first, R4 lesson); 32 cand/row -> rank-select top-8 ->
//   fp64 refine vs fp32 originals -> exact top-4 (value desc, index asc).
// Fallback: fp32 LDS-tiled kernel if ws too small.

#define NBATCH 4
#define NQ 4096
#define NM 8192
#define KD 128

typedef unsigned short ushort_t;
typedef __attribute__((ext_vector_type(8))) short bf16x8;
typedef __attribute__((ext_vector_type(4))) float f32x4;

#define BETTER64(v, i, w, j) (((v) > (w)) || ((v) == (w) && (i) < (j)))

__device__ inline float fmed3(float a, float b, float c) {
#if __has_builtin(__builtin_amdgcn_fmed3f)
  return __builtin_amdgcn_fmed3f(a, b, c);
#else
  return fmaxf(fminf(a, b), fminf(fmaxf(a, b), c));
#endif
}

__device__ inline ushort_t f2bf(float f) {
  unsigned u = __float_as_uint(f);
  u += 0x7fffu + ((u >> 16) & 1u);  // RNE
  return (ushort_t)(u >> 16);
}

// ---------------- K0: convert + swizzle (unchanged from R7) ----------------
__global__ __launch_bounds__(256) void wr_cvt(const float* __restrict__ qry,
                                              const float* __restrict__ img,
                                              ushort_t* __restrict__ qb,
                                              int4* __restrict__ ib) {
  const int blk = (int)blockIdx.x;
  const int tid = (int)threadIdx.x;
  if (blk < 2048) {
    const int t = blk * 256 + tid;  // 0..524287
    const float4 v = ((const float4*)qry)[t];
    ushort4 o;
    o.x = f2bf(v.x); o.y = f2bf(v.y); o.z = f2bf(v.z); o.w = f2bf(v.w);
    ((ushort4*)qb)[t] = o;
  } else {
    const int tg = blk - 2048;  // 0..1023 : one 32-m tile (= 2 half-tiles)
    const int b = tg >> 8;
    const int tile = tg & 255;
    __shared__ __align__(16) ushort_t T[32 * 128];
    {
      const int r = tid >> 3;
      const int seg = tid & 7;
      const float* src = img + ((size_t)(b * NM + tile * 32 + r)) * KD + seg * 16;
      ushort_t tmp[16];
#pragma unroll
      for (int i = 0; i < 4; ++i) {
        const float4 v = ((const float4*)src)[i];
        tmp[i * 4 + 0] = f2bf(v.x);
        tmp[i * 4 + 1] = f2bf(v.y);
        tmp[i * 4 + 2] = f2bf(v.z);
        tmp[i * 4 + 3] = f2bf(v.w);
      }
      const int c0 = (seg * 16 + r * 8) & 127;
      const int c1 = (seg * 16 + 8 + r * 8) & 127;
      *(int4*)&T[r * 128 + c0] = *(const int4*)&tmp[0];
      *(int4*)&T[r * 128 + c1] = *(const int4*)&tmp[8];
    }
    __syncthreads();
    int4* dstt = ib + ((size_t)b * 256 + tile) * 512;
#pragma unroll
    for (int h = 0; h < 2; ++h) {
      const int n = tid + h * 256;
      const int l = n & 63;
      const int ks = (n >> 6) & 3;
      const int htl = n >> 8;
      const int row = htl * 16 + (l & 15);
      const int col = ks * 32 + (l >> 4) * 8;
      dstt[n] = *(const int4*)&T[row * 128 + ((col + row * 8) & 127)];
    }
  }
}

// ---------------- K1: MFMA screen + fp64 refine ----------------
__global__ __launch_bounds__(512, 1) void wr_mfma(const float* __restrict__ qry,
                                                  const float* __restrict__ img,
                                                  const ushort_t* __restrict__ qb,
                                                  const int4* __restrict__ ib,
                                                  int* __restrict__ out) {
  const int bid = (int)blockIdx.x;               // 0..255
  const int b = (bid & 7) >> 1;                  // batch pinned to XCD pair
  const int qt = ((bid >> 3) << 1) | (bid & 1);  // 0..63
  const int qbase = qt * 64;

  const int tid = (int)threadIdx.x;
  const int lane = tid & 63;
  const int w = tid >> 6;        // 0..7 -> m-eighth (64 half-tiles of 16 m)
  const int q15 = lane & 15;
  const int quad = lane >> 4;    // 0..3

  const ushort_t* Qb = qb + ((size_t)b * NQ + qbase) * KD;
  const int4* ibc = ib + (size_t)b * 131072;

  // query fragments pinned: 4 strips of 16 q. B[n=q15][k = ks*32 + quad*8 + j]
  bf16x8 bfrag[4][4];  // [strip][ks] -> 64 VGPRs
#pragma unroll
  for (int s = 0; s < 4; ++s)
#pragma unroll
    for (int ks = 0; ks < 4; ++ks)
      bfrag[s][ks] =
          *(const bf16x8*)(Qb + (size_t)(s * 16 + q15) * KD + ks * 32 + quad * 8);

  float tch[4][4];  // one packed-key top-4 chain per strip
#pragma unroll
  for (int s = 0; s < 4; ++s)
#pragma unroll
    for (int e = 0; e < 4; ++e) tch[s][e] = -FLT_MAX;

  bf16x8 B0[4], B1[4], B2[4];  // 3-deep ring, 16 regs each

  auto loadH = [&](bf16x8* R, int h) {
    const int4* p = ibc + (((w * 64 + h) << 8) + lane);
#pragma unroll
    for (int ks = 0; ks < 4; ++ks) R[ks] = *(const bf16x8*)(p + ks * 64);
  };

  int hl = 3;
  int vb = 2047 - 4 * quad;  // key base; m_local = 16*h + 4*quad + r  (< 1024)

  auto step = [&](bf16x8* R) {
    f32x4 a[4];
#pragma unroll
    for (int s = 0; s < 4; ++s) a[s] = {0.f, 0.f, 0.f, 0.f};
    // all 16 MFMAs consume R before the refill below (ring-reuse hazard)
#pragma unroll
    for (int ks = 0; ks < 4; ++ks)
#pragma unroll
      for (int s = 0; s < 4; ++s)
        a[s] = __builtin_amdgcn_mfma_f32_16x16x32_bf16(R[ks], bfrag[s][ks], a[s],
                                                       0, 0, 0);
    if (hl < 64) loadH(R, hl);  // refill for use 3 steps later
    ++hl;
#pragma unroll
    for (int s = 0; s < 4; ++s) {
#pragma unroll
      for (int r = 0; r < 4; ++r) {
        const unsigned kr = (unsigned)(vb - r);
        const float k =
            __uint_as_float((__float_as_uint(a[s][r]) & 0xFFFFF800u) | kr);
        tch[s][3] = fmed3(k, tch[s][2], tch[s][3]);
        tch[s][2] = fmed3(k, tch[s][1], tch[s][2]);
        tch[s][1] = fmed3(k, tch[s][0], tch[s][1]);
        tch[s][0] = fmaxf(tch[s][0], k);
      }
    }
    vb -= 16;
  };

  loadH(B0, 0);
  loadH(B1, 1);
  loadH(B2, 2);
  for (int g = 0; g < 21; ++g) { step(B0); step(B1); step(B2); }
  step(B0);  // half-tile 63

  // ---- quad-tree merge per strip (snapshot donor regs BEFORE mutating) ----
#pragma unroll
  for (int s = 0; s < 4; ++s) {
    float k4[4];
#pragma unroll
    for (int e = 0; e < 4; ++e) k4[e] = __shfl_down(tch[s][e], 32, 64);
#pragma unroll
    for (int e = 0; e < 4; ++e) {
      const float k = k4[e];
      tch[s][3] = fmed3(k, tch[s][2], tch[s][3]);
      tch[s][2] = fmed3(k, tch[s][1], tch[s][2]);
      tch[s][1] = fmed3(k, tch[s][0], tch[s][1]);
      tch[s][0] = fmaxf(tch[s][0], k);
    }
#pragma unroll
    for (int e = 0; e < 4; ++e) k4[e] = __shfl_down(tch[s][e], 16, 64);
#pragma unroll
    for (int e = 0; e < 4; ++e) {
      const float k = k4[e];
      tch[s][3] = fmed3(k, tch[s][2], tch[s][3]);
      tch[s][2] = fmed3(k, tch[s][1], tch[s][2]);
      tch[s][1] = fmed3(k, tch[s][0], tch[s][1]);
      tch[s][0] = fmaxf(tch[s][0], k);
    }
  }

  // ---- 32 candidates per q-row (8 eighths x 4), 64 rows ----
  __shared__ float ck[64][33];
  __shared__ int top8[64][8];
  __shared__ double pd[64][8];
  __shared__ int pi[64][8];

  if (lane < 16) {
#pragma unroll
    for (int s = 0; s < 4; ++s)
#pragma unroll
      for (int e = 0; e < 4; ++e) ck[s * 16 + q15][w * 4 + e] = tch[s][e];
  }
  __syncthreads();

  // ---- rank-select top-8 of 32 packed keys per row (ranks unique) ----
  for (int p = tid; p < 2048; p += 512) {
    const int q = p >> 5;
    const int j = p & 31;
    const float k = ck[q][j];
    int rank = 0;
#pragma unroll 8
    for (int i = 0; i < 32; ++i) {
      const float o = ck[q][i];
      rank += (o > k) || (o == k && i < j);
    }
    if (rank < 8) {
      const unsigned bits = __float_as_uint(k);
      top8[q][rank] = (j >> 2) * 1024 + 2047 - (int)(bits & 0x7FFu);
    }
  }
  __syncthreads();

  // ---- fp64 refine: one candidate per thread (64 rows x 8) ----
  {
    const int q = tid >> 3;
    const int slot = tid & 7;
    const int m = top8[q][slot];
    const float* qrow = qry + ((size_t)b * NQ + qbase + q) * KD;
    const float* irow = img + ((size_t)b * NM + m) * KD;
    double s0 = 0.0, s1 = 0.0, s2 = 0.0, s3 = 0.0;
#pragma unroll
    for (int k = 0; k < KD; k += 4) {
      const float4 xv = *(const float4*)(qrow + k);
      const float4 yv = *(const float4*)(irow + k);
      s0 = fma((double)xv.x, (double)yv.x, s0);
      s1 = fma((double)xv.y, (double)yv.y, s1);
      s2 = fma((double)xv.z, (double)yv.z, s2);
      s3 = fma((double)xv.w, (double)yv.w, s3);
    }
    pd[q][slot] = (s0 + s1) + (s2 + s3);
    pi[q][slot] = m;
  }
  __syncthreads();

  // ---- exact top-4 of 8 refined, (value desc, index asc) ----
  if (tid < 64) {
    const int q = tid;
    double fv[4];
    int fi[4];
#pragma unroll
    for (int e = 0; e < 4; ++e) { fv[e] = -DBL_MAX; fi[e] = 0x7fffffff; }
    for (int sl = 0; sl < 8; ++sl) {
      const double v = pd[q][sl];
      const int m = pi[q][sl];
      const bool b0 = BETTER64(v, m, fv[0], fi[0]);
      const bool b1 = BETTER64(v, m, fv[1], fi[1]);
      const bool b2 = BETTER64(v, m, fv[2], fi[2]);
      const bool b3 = BETTER64(v, m, fv[3], fi[3]);
      fv[3] = b2 ? fv[2] : (b3 ? v : fv[3]);
      fi[3] = b2 ? fi[2] : (b3 ? m : fi[3]);
      fv[2] = b1 ? fv[1] : (b2 ? v : fv[2]);
      fi[2] = b1 ? fi[1] : (b2 ? m : fi[2]);
      fv[1] = b0 ? fv[0] : (b1 ? v : fv[1]);
      fi[1] = b0 ? fi[0] : (b1 ? m : fi[1]);
      fv[0] = b0 ? v : fv[0];
      fi[0] = b0 ? m : fi[0];
    }
    int4 o;
    o.x = fi[0]; o.y = fi[1]; o.z = fi[2]; o.w = fi[3];
    *(int4*)(out + ((size_t)b * NQ + qbase + q) * 4) = o;
  }
}

// ---------------- Fallback: fp32 LDS-tiled kernel (ws too small) ----------------
#define QT 64
#define MT 128
#define KC 64
#define NTHREADS 512

__global__ __launch_bounds__(NTHREADS) void wr_main(const float* __restrict__ qry,
                                                    const float* __restrict__ img,
                                                    int* __restrict__ out) {
  __shared__ __align__(16) float A_lds[KD * QT];
  __shared__ __align__(16) float B_lds[KC * MT];

  const int t = (int)threadIdx.x;
  const int b = (int)blockIdx.x >> 6;
  const int qbase = ((int)blockIdx.x & 63) * QT;

  const float* qp = qry + ((size_t)b * NQ + qbase) * KD;
  const float* ip = img + (size_t)b * NM * KD;

  {
    const int r = t >> 3;
    const int kc = t & 7;
    const float* src = qp + (size_t)r * KD;
#pragma unroll
    for (int i = 0; i < 4; ++i) {
      const int k0 = kc * 4 + i * 32;
      const float4 v = *(const float4*)(src + k0);
      A_lds[(k0 + 0) * QT + r] = v.x;
      A_lds[(k0 + 1) * QT + r] = v.y;
      A_lds[(k0 + 2) * QT + r] = v.z;
      A_lds[(k0 + 3) * QT + r] = v.w;
    }
  }

  const int qi = t >> 5;
  const int mi = t & 31;

  float tv[4][4];
  int ti[4][4];
#pragma unroll
  for (int j = 0; j < 4; ++j)
#pragma unroll
    for (int s = 0; s < 4; ++s) { tv[j][s] = -FLT_MAX; ti[j][s] = 0x7fffffff; }

  for (int tile = 0; tile < NM / MT; ++tile) {
    const int mbase = tile * MT;
    float acc[4][4];
#pragma unroll
    for (int j = 0; j < 4; ++j)
#pragma unroll
      for (int s = 0; s < 4; ++s) acc[j][s] = 0.0f;

    for (int kb = 0; kb < KD; kb += KC) {
      __syncthreads();
      {
        const int r = t >> 2;
        const int kc = t & 3;
        const float* src = ip + (size_t)(mbase + r) * KD + kb;
#pragma unroll
        for (int i = 0; i < 4; ++i) {
          const int k0 = kc * 4 + i * 16;
          const float4 v = *(const float4*)(src + k0);
          B_lds[(k0 + 0) * MT + r] = v.x;
          B_lds[(k0 + 1) * MT + r] = v.y;
          B_lds[(k0 + 2) * MT + r] = v.z;
          B_lds[(k0 + 3) * MT + r] = v.w;
        }
      }
      __syncthreads();

#pragma unroll 8
      for (int k = 0; k < KC; ++k) {
        const float4 av = *(const float4*)&A_lds[(kb + k) * QT + qi * 4];
        const float4 bv = *(const float4*)&B_lds[k * MT + mi * 4];
        acc[0][0] = fmaf(av.x, bv.x, acc[0][0]);
        acc[0][1] = fmaf(av.x, bv.y, acc[0][1]);
        acc[0][2] = fmaf(av.x, bv.z, acc[0][2]);
        acc[0][3] = fmaf(av.x, bv.w, acc[0][3]);
        acc[1][0] = fmaf(av.y, bv.x, acc[1][0]);
        acc[1][1] = fmaf(av.y, bv.y, acc[1][1]);
        acc[1][2] = fmaf(av.y, bv.z, acc[1][2]);
        acc[1][3] = fmaf(av.y, bv.w, acc[1][3]);
        acc[2][0] = fmaf(av.z, bv.x, acc[2][0]);
        acc[2][1] = fmaf(av.z, bv.y, acc[2][1]);
        acc[2][2] = fmaf(av.z, bv.z, acc[2][2]);
        acc[2][3] = fmaf(av.z, bv.w, acc[2][3]);
        acc[3][0] = fmaf(av.w, bv.x, acc[3][0]);
        acc[3][1] = fmaf(av.w, bv.y, acc[3][1]);
        acc[3][2] = fmaf(av.w, bv.z, acc[3][2]);
        acc[3][3] = fmaf(av.w, bv.w, acc[3][3]);
      }
    }

#pragma unroll
    for (int j = 0; j < 4; ++j) {
#pragma unroll
      for (int s = 0; s < 4; ++s) {
        const float v = acc[j][s];
        const int m = mbase + mi * 4 + s;
        const bool b0 = v > tv[j][0];
        const bool b1 = v > tv[j][1];
        const bool b2 = v > tv[j][2];
        const bool b3 = v > tv[j][3];
        tv[j][3] = b2 ? tv[j][2] : (b3 ? v : tv[j][3]);
        ti[j][3] = b2 ? ti[j][2] : (b3 ? m : ti[j][3]);
        tv[j][2] = b1 ? tv[j][1] : (b2 ? v : tv[j][2]);
        ti[j][2] = b1 ? ti[j][1] : (b2 ? m : ti[j][2]);
        tv[j][1] = b0 ? tv[j][0] : (b1 ? v : tv[j][1]);
        ti[j][1] = b0 ? ti[j][0] : (b1 ? m : ti[j][1]);
        tv[j][0] = b0 ? v : tv[j][0];
        ti[j][0] = b0 ? m : ti[j][0];
      }
    }
  }

  __syncthreads();
  int* idx_lds = (int*)B_lds;
#pragma unroll
  for (int j = 0; j < 4; ++j)
#pragma unroll
    for (int s = 0; s < 4; ++s)
      idx_lds[(qi * 4 + j) * 128 + mi * 4 + s] = ti[j][s];
  __syncthreads();

  double* pv = (double*)A_lds;
  int* piL = (int*)(A_lds + 4096);
  {
    const int r = t >> 3;
    const int slot = t & 7;
    const float* qrow = qp + (size_t)r * KD;
    double bv[4];
    int bi[4];
#pragma unroll
    for (int e = 0; e < 4; ++e) { bv[e] = -DBL_MAX; bi[e] = 0x7fffffff; }

    for (int c = 0; c < 16; ++c) {
      const int m = idx_lds[r * 128 + slot * 16 + c];
      const float* irow = ip + (size_t)m * KD;
      double s0 = 0.0, s1 = 0.0, s2 = 0.0, s3 = 0.0;
#pragma unroll
      for (int k = 0; k < KD; k += 4) {
        const float4 xv = *(const float4*)(qrow + k);
        const float4 yv = *(const float4*)(irow + k);
        s0 = fma((double)xv.x, (double)yv.x, s0);
        s1 = fma((double)xv.y, (double)yv.y, s1);
        s2 = fma((double)xv.z, (double)yv.z, s2);
        s3 = fma((double)xv.w, (double)yv.w, s3);
      }
      const double v = (s0 + s1) + (s2 + s3);
      const bool b0 = BETTER64(v, m, bv[0], bi[0]);
      const bool b1 = BETTER64(v, m, bv[1], bi[1]);
      const bool b2 = BETTER64(v, m, bv[2], bi[2]);
      const bool b3 = BETTER64(v, m, bv[3], bi[3]);
      bv[3] = b2 ? bv[2] : (b3 ? v : bv[3]);
      bi[3] = b2 ? bi[2] : (b3 ? m : bi[3]);
      bv[2] = b1 ? bv[1] : (b2 ? v : bv[2]);
      bi[2] = b1 ? bi[1] : (b2 ? m : bi[2]);
      bv[1] = b0 ? bv[0] : (b1 ? v : bv[1]);
      bi[1] = b0 ? bi[0] : (b1 ? m : bi[1]);
      bv[0] = b0 ? v : bv[0];
      bi[0] = b0 ? m : bi[0];
    }
#pragma unroll
    for (int e = 0; e < 4; ++e) {
      pv[t * 4 + e] = bv[e];
      piL[t * 4 + e] = bi[e];
    }
  }
  __syncthreads();

  if (t < QT) {
    double fv[4];
    int fi[4];
#pragma unroll
    for (int e = 0; e < 4; ++e) { fv[e] = -DBL_MAX; fi[e] = 0x7fffffff; }
    for (int sl = 0; sl < 8; ++sl) {
#pragma unroll
      for (int e = 0; e < 4; ++e) {
        const double v = pv[(t * 8 + sl) * 4 + e];
        const int m = piL[(t * 8 + sl) * 4 + e];
        const bool b0 = BETTER64(v, m, fv[0], fi[0]);
        const bool b1 = BETTER64(v, m, fv[1], fi[1]);
        const bool b2 = BETTER64(v, m, fv[2], fi[2]);
        const bool b3 = BETTER64(v, m, fv[3], fi[3]);
        fv[3] = b2 ? fv[2] : (b3 ? v : fv[3]);
        fi[3] = b2 ? fi[2] : (b3 ? m : fi[3]);
        fv[2] = b1 ? fv[1] : (b2 ? v : fv[2]);
        fi[2] = b1 ? fi[1] : (b2 ? m : fi[2]);
        fv[1] = b0 ? fv[0] : (b1 ? v : fv[1]);
        fi[1] = b0 ? fi[0] : (b1 ? m : fi[1]);
        fv[0] = b0 ? v : fv[0];
        fi[0] = b0 ? m : fi[0];
      }
    }
    int4 o;
    o.x = fi[0]; o.y = fi[1]; o.z = fi[2]; o.w = fi[3];
    *(int4*)(out + ((size_t)b * NQ + qbase + t) * 4) = o;
  }
}

extern "C" void kernel_launch(void* const* d_in, const int* in_sizes, int n_in,
                              void* d_out, int out_size, void* d_ws, size_t ws_size,
                              hipStream_t stream) {
  const float* qry = (const float*)d_in[0];  // (4, 4096, 128) fp32
  const float* img = (const float*)d_in[1];  // (4, 8192, 128) fp32
  int* out = (int*)d_out;                    // (4, 4096, 4) int32

  const size_t qbBytes = (size_t)NBATCH * NQ * KD * sizeof(ushort_t);  // 4 MB
  const size_t ibBytes = (size_t)NBATCH * NM * KD * sizeof(ushort_t);  // 8 MB

  if (ws_size >= qbBytes + ibBytes) {
    ushort_t* qb = (ushort_t*)d_ws;
    int4* ib = (int4*)((char*)d_ws + qbBytes);
    wr_cvt<<<3072, 256, 0, stream>>>(qry, img, qb, ib);
    wr_mfma<<<256, 512, 0, stream>>>(qry, img, qb, ib, out);
  } else {
    wr_main<<<NBATCH * (NQ / QT), NTHREADS, 0, stream>>>(qry, img, out);
  }
}